// Round 15
// baseline (1679.717 us; speedup 1.0000x reference)
//
#include <hip/hip_runtime.h>
#include <math.h>

#define NB   4096
#define NIN  768
#define NLAT 24576
#define K2   1536   // [Ah|Al] x [Bh|Bh]
#define KT2  24     // K2/64

// f32 fallback GEMM tiling
#define BM 128
#define BN 128
#define BK 16
#define LDT 132

#define CAND_CAP 512
#define BAND_CAP 160
#define MAIN_CAP 64
#define AUX_CAP  1024
#define SELT     1024
#define GRP      6

#define CM_CAP 768
#define CA_CAP 2560
#define BB_CAP 384

// dynamic LDS layout for k_selectFB (old select12, fallback path)
#define OFF_K16  0
#define OFF_REDF 49152
#define OFF_CTRL 49664
#define OFF_PCNT 49792
#define OFF_CKM  50176
#define OFF_CIM  52224
#define OFF_CKA  54272
#define OFF_CIA  56320
#define OFF_BIM  58368
#define OFF_BIA  59008
#define OFF_BVM  59648
#define OFF_BVA  60928
#define OFF_BSM  62208
#define OFF_BSA  62368
#define OFF_REDI 62528
#define SMEM_SEL 62592

typedef __bf16 bf16x8 __attribute__((ext_vector_type(8)));
typedef float  f32x4  __attribute__((ext_vector_type(4)));

__device__ __forceinline__ unsigned fkey(float f) {
  unsigned u = __float_as_uint(f);
  return u ^ ((unsigned)((int)u >> 31) | 0x80000000u);  // monotone total order
}
__device__ __forceinline__ float keyinv(unsigned u) {
  unsigned s = (u & 0x80000000u) ? (u ^ 0x80000000u) : ~u;
  return __uint_as_float(s);
}
__device__ __forceinline__ float zup(float p) {
  p = fminf(fmaxf(p, 1e-7f), 0.5f);
  float t = sqrtf(-2.0f * logf(p));
  return t - (2.30753f + 0.27061f * t) / (1.0f + 0.99229f * t + 0.04481f * t * t);
}

#define GLOAD16(g, l) __builtin_amdgcn_global_load_lds( \
    (const __attribute__((address_space(1))) unsigned int*)(g), \
    (__attribute__((address_space(3))) unsigned int*)(l), 16, 0, 0)

// ---------------- dead bitset ----------------
__global__ __launch_bounds__(256) void k_deadbits(const int* __restrict__ miss,
                                                  unsigned* __restrict__ bits) {
  int j = blockIdx.x * 256 + threadIdx.x;
  unsigned long long b = __ballot(miss[j] >= 1);
  if ((threadIdx.x & 63) == 0) {
    int w = j >> 5;
    bits[w] = (unsigned)b;
    bits[w + 1] = (unsigned)(b >> 32);
  }
}

// ---------------- global dead count ----------------
__global__ __launch_bounds__(256) void k_ndead(const unsigned* __restrict__ bits,
                                               int* __restrict__ out) {
  __shared__ int w[4];
  int t = threadIdx.x;
  int c = 0;
  for (int i = t; i < NLAT / 32; i += 256) c += __popc(bits[i]);
#pragma unroll
  for (int o = 32; o; o >>= 1) c += __shfl_xor(c, o);
  if ((t & 63) == 0) w[t >> 6] = c;
  __syncthreads();
  if (t == 0) out[0] = w[0] + w[1] + w[2] + w[3];
}

// ---------------- W_dec -> Wt bf16 ----------------
__global__ __launch_bounds__(256) void k_transpose(const float* __restrict__ src,
                                                   __bf16* __restrict__ dst) {
  __shared__ float tile[32][33];
  int bx = blockIdx.x * 32;
  int by = blockIdx.y * 32;
  int tx = threadIdx.x, ty = threadIdx.y;
  for (int i = ty; i < 32; i += 8)
    tile[i][tx] = src[(size_t)(by + i) * NLAT + bx + tx];
  __syncthreads();
  for (int i = ty; i < 32; i += 8)
    dst[(size_t)(bx + i) * NIN + by + tx] = (__bf16)tile[tx][i];
}

// ---- packs ----
__global__ __launch_bounds__(256) void k_pack_a(const float* __restrict__ x,
    const float* __restrict__ bvec, __bf16* __restrict__ A2) {
  const int mt = blockIdx.x, kt = blockIdx.y, t = threadIdx.x;
  __bf16* out = A2 + (((size_t)mt * KT2 + kt) << 13);
#pragma unroll
  for (int i = 0; i < 32; ++i) {
    int idx = i * 256 + t;
    int r = idx >> 6, c2 = idx & 63;
    int kk = c2 ^ ((r & 7) << 3);
    int kg = kt * 64 + kk;
    int k = kg >= 768 ? kg - 768 : kg;
    bool lo = (kg >= 768);
    float v = x[(size_t)(mt * 128 + r) * NIN + k] - bvec[k];
    __bf16 h = (__bf16)v;
    out[idx] = lo ? (__bf16)(v - (float)h) : h;
  }
}

__global__ __launch_bounds__(256) void k_pack_b(const float* __restrict__ We,
    __bf16* __restrict__ B2) {
  const int nt = blockIdx.x, kt = blockIdx.y, t = threadIdx.x;
  __bf16* out = B2 + (((size_t)nt * KT2 + kt) << 13);
#pragma unroll
  for (int i = 0; i < 32; ++i) {
    int idx = i * 256 + t;
    int r = idx >> 6, c2 = idx & 63;
    int kk = c2 ^ ((r & 7) << 3);
    int kg = kt * 64 + kk;
    int k = kg >= 768 ? kg - 768 : kg;
    float v = We[(size_t)(nt * 128 + r) * NIN + k];
    out[idx] = (__bf16)v;
  }
}

// ---------------- bf16 MFMA GEMM (XCD-swizzled block map) ----------------
__global__ __launch_bounds__(256) void k_gemm_bf16(
    const __bf16* __restrict__ A2, const __bf16* __restrict__ B2,
    const float* __restrict__ be, float* __restrict__ apre) {
  __shared__ char sA[16384];
  __shared__ char sB[16384];
  const int t = threadIdx.x;
  const int lane = t & 63, wave = t >> 6;
  // bijective XCD swizzle: nwg=6144=8*768; xcd gets contiguous chunk
  int flat = blockIdx.y * 32 + blockIdx.x;
  int nf = (flat & 7) * 768 + (flat >> 3);
  const int mt = nf & 31, nt = nf >> 5;
  const int wm = wave >> 1, wn = wave & 1;

  int aoff[4][2], boff[4][2];
#pragma unroll
  for (int f = 0; f < 4; ++f) {
    int ra = wm * 64 + f * 16 + (lane & 15);
    int rb = wn * 64 + f * 16 + (lane & 15);
#pragma unroll
    for (int kk = 0; kk < 2; ++kk) {
      int c = kk * 64 + (lane >> 4) * 16;
      aoff[f][kk] = ra * 128 + (c ^ ((ra & 7) << 4));
      boff[f][kk] = rb * 128 + (c ^ ((rb & 7) << 4));
    }
  }
  f32x4 acc[4][4] = {};
  const char* gA = (const char*)(A2 + (((size_t)mt * KT2) << 13));
  const char* gB = (const char*)(B2 + (((size_t)nt * KT2) << 13));
  for (int kt = 0; kt < KT2; ++kt) {
    const char* tA = gA + ((size_t)kt << 14);
    const char* tB = gB + ((size_t)kt << 14);
#pragma unroll
    for (int i = 0; i < 4; ++i) {
      int chunk = (i * 4 + wave) * 1024;
      GLOAD16(tA + chunk + lane * 16, sA + chunk);
      GLOAD16(tB + chunk + lane * 16, sB + chunk);
    }
    __syncthreads();
#pragma unroll
    for (int kk = 0; kk < 2; ++kk) {
      bf16x8 a[4], b[4];
#pragma unroll
      for (int f = 0; f < 4; ++f) {
        a[f] = *(const bf16x8*)(sA + aoff[f][kk]);
        b[f] = *(const bf16x8*)(sB + boff[f][kk]);
      }
#pragma unroll
      for (int mi = 0; mi < 4; ++mi)
#pragma unroll
        for (int ni = 0; ni < 4; ++ni)
          acc[mi][ni] = __builtin_amdgcn_mfma_f32_16x16x32_bf16(a[mi], b[ni], acc[mi][ni], 0, 0, 0);
    }
    __syncthreads();
  }
  const int m0 = mt * 128 + wm * 64, n0 = nt * 128 + wn * 64;
#pragma unroll
  for (int ni = 0; ni < 4; ++ni) {
    int n = n0 + ni * 16 + (lane & 15);
    float bb = be[n];
#pragma unroll
    for (int mi = 0; mi < 4; ++mi) {
      int mbase = m0 + mi * 16 + (lane >> 4) * 4;
#pragma unroll
      for (int q = 0; q < 4; ++q)
        apre[(size_t)(mbase + q) * NLAT + n] = acc[mi][ni][q] + bb;
    }
  }
}

// ---------------- f32 fallback GEMM ----------------
__global__ __launch_bounds__(256) void k_encgemm_f32(
    const float* __restrict__ x, const float* __restrict__ bvec,
    const float* __restrict__ We, const float* __restrict__ be,
    float* __restrict__ apre) {
  __shared__ float As[BK][LDT];
  __shared__ float Bs[BK][LDT];
  const int t = threadIdx.x;
  const int m0 = blockIdx.x * BM;
  const int n0 = blockIdx.y * BN;
  const int lane = t & 63, wave = t >> 6;
  const int cn = ((wave & 1) * 8 + (lane & 7)) * 8;
  const int cm = ((wave >> 1) * 8 + (lane >> 3)) * 8;
  float acc[8][8] = {};
  const float* xb = x + (size_t)m0 * NIN;
  const float* wb = We + (size_t)n0 * NIN;
  for (int k0 = 0; k0 < NIN; k0 += BK) {
#pragma unroll
    for (int i = 0; i < 2; ++i) {
      int e = t + i * 256;
      int row = e >> 2, q = e & 3;
      float4 bv = *(const float4*)(bvec + k0 + q * 4);
      float4 av = *(const float4*)(xb + (size_t)row * NIN + k0 + q * 4);
      av.x -= bv.x; av.y -= bv.y; av.z -= bv.z; av.w -= bv.w;
      As[q * 4 + 0][row] = av.x; As[q * 4 + 1][row] = av.y;
      As[q * 4 + 2][row] = av.z; As[q * 4 + 3][row] = av.w;
      float4 wv = *(const float4*)(wb + (size_t)row * NIN + k0 + q * 4);
      Bs[q * 4 + 0][row] = wv.x; Bs[q * 4 + 1][row] = wv.y;
      Bs[q * 4 + 2][row] = wv.z; Bs[q * 4 + 3][row] = wv.w;
    }
    __syncthreads();
#pragma unroll
    for (int kk = 0; kk < BK; ++kk) {
      float a0[8], b0[8];
      *(float4*)&a0[0] = *(const float4*)&As[kk][cm];
      *(float4*)&a0[4] = *(const float4*)&As[kk][cm + 4];
      *(float4*)&b0[0] = *(const float4*)&Bs[kk][cn];
      *(float4*)&b0[4] = *(const float4*)&Bs[kk][cn + 4];
#pragma unroll
      for (int i = 0; i < 8; ++i)
#pragma unroll
        for (int j = 0; j < 8; ++j)
          acc[i][j] = fmaf(a0[i], b0[j], acc[i][j]);
    }
    __syncthreads();
  }
  float bb[8];
  *(float4*)&bb[0] = *(const float4*)(be + n0 + cn);
  *(float4*)&bb[4] = *(const float4*)(be + n0 + cn + 4);
#pragma unroll
  for (int i = 0; i < 8; ++i) {
    float4 v0 = make_float4(acc[i][0] + bb[0], acc[i][1] + bb[1],
                            acc[i][2] + bb[2], acc[i][3] + bb[3]);
    float4 v1 = make_float4(acc[i][4] + bb[4], acc[i][5] + bb[5],
                            acc[i][6] + bb[6], acc[i][7] + bb[7]);
    float* orow = apre + (size_t)(m0 + cm + i) * NLAT + n0 + cn;
    *(float4*)orow = v0;
    *(float4*)(orow + 4) = v1;
  }
}

// ------------- per-row analytic-threshold select + histogram rank + fused emit ----
__global__ __launch_bounds__(1024) void k_select15(
    const float* apre, const float* __restrict__ x,
    const float* __restrict__ bvec, const float* __restrict__ We,
    const float* __restrict__ be, const unsigned* __restrict__ dbits,
    const int* __restrict__ kptr, const int* __restrict__ akptr,
    const int* __restrict__ ndeadP,
    float* __restrict__ alpha, float* mask,
    int* __restrict__ cnts, int* __restrict__ mIdxG, float* __restrict__ mValG,
    int* __restrict__ aIdxG, float* __restrict__ aValG,
    int* __restrict__ flags) {
  __shared__ float redF[32];
  __shared__ float statF[4];
  __shared__ int ctrl[24];
  __shared__ int histM[256];
  __shared__ int histA[256];
  __shared__ uint2 cM[CM_CAP];
  __shared__ uint2 cA[CA_CAP];
  __shared__ uint2 bbM[BB_CAP];
  __shared__ uint2 bbA[BB_CAP];
  __shared__ int biM[BAND_CAP];
  __shared__ int biA[BAND_CAP];
  __shared__ double bvM[BAND_CAP];
  __shared__ double bvA[BAND_CAP];
  __shared__ unsigned char bsM[BAND_CAP];
  __shared__ unsigned char bsA[BAND_CAP];
  unsigned* uctrl = (unsigned*)ctrl;

  const int t = threadIdx.x;
  const int r = blockIdx.x;
  const int lane = t & 63, wave = t >> 6;   // 16 waves

  if (t < 24) ctrl[t] = 0;
  if (t >= 256 && t < 512) histM[t - 256] = 0;
  else if (t >= 512 && t < 768) histA[t - 512] = 0;

  // ---- scan 1: stats + dead bits ----
  const uint4* rowp = (const uint4*)(apre + (size_t)r * NLAT);
  unsigned dm = 0;
  float s1 = 0.f, s2 = 0.f;
#pragma unroll
  for (int i = 0; i < GRP; ++i) {
    int g = t + SELT * i;
    uint4 rv = rowp[g];
    unsigned nb = (dbits[g >> 3] >> ((g & 7) * 4)) & 0xFu;
    dm |= nb << (4 * i);
    float vs[4] = {__uint_as_float(rv.x), __uint_as_float(rv.y),
                   __uint_as_float(rv.z), __uint_as_float(rv.w)};
#pragma unroll
    for (int q = 0; q < 4; ++q) { float v = vs[q]; s1 += v; s2 += v * v; }
  }
#pragma unroll
  for (int o = 32; o; o >>= 1) { s1 += __shfl_xor(s1, o); s2 += __shfl_xor(s2, o); }
  if (lane == 0) { redF[wave] = s1; redF[16 + wave] = s2; }
  __syncthreads();
  if (wave == 0) {
    float a0 = (lane < 16) ? redF[lane] : 0.f;
    float a1 = (lane < 16) ? redF[16 + lane] : 0.f;
#pragma unroll
    for (int o = 32; o; o >>= 1) { a0 += __shfl_xor(a0, o); a1 += __shfl_xor(a1, o); }
    if (lane == 0) {
      float mu = a0 / (float)NLAT;
      float var = fmaxf(a1 / (float)NLAT - mu * mu, 1e-20f);
      statF[0] = mu; statF[1] = sqrtf(var);
    }
  }
  __syncthreads();

  int kmain = kptr[0]; if (kmain > MAIN_CAP) kmain = MAIN_CAP;
  int kaux  = akptr[0]; if (kaux > AUX_CAP)  kaux  = AUX_CAP;
  const int ndead = ndeadP[0];
  int kauxE = kaux > ndead ? ndead : kaux;
  const bool mainOn = (kmain > 0);
  const bool auxOn  = (kauxE > 0);
  const float mu = statF[0], sg = statF[1];
  unsigned TkM = 0xFFFFFFFFu, TkA = 0xFFFFFFFFu;
  if (mainOn) TkM = fkey(mu + sg * zup(8.f * kmain / (float)NLAT));
  if (auxOn) {
    float facA = (3.f * kauxE > 2048.f) ? 2.f : 3.f;
    TkA = fkey(mu + sg * zup(facA * kauxE / (float)ndead));
  }

  // ---- scan 2: extract candidates into LDS; track max key ----
  unsigned mxM = 0u, mxA = 0u;
#pragma unroll
  for (int i = 0; i < GRP; ++i) {
    int g = t + SELT * i;
    uint4 rv = rowp[g];
    unsigned nb = (dm >> (4 * i)) & 0xFu;
    float vs[4] = {__uint_as_float(rv.x), __uint_as_float(rv.y),
                   __uint_as_float(rv.z), __uint_as_float(rv.w)};
#pragma unroll
    for (int q = 0; q < 4; ++q) {
      unsigned kk = fkey(vs[q]);
      unsigned j = (unsigned)(4 * g + q);
      if (mainOn && kk >= TkM) {
        mxM = kk > mxM ? kk : mxM;
        int p = atomicAdd(&ctrl[0], 1);
        if (p < CM_CAP) { cM[p].x = kk; cM[p].y = j; }
      }
      if (auxOn && ((nb >> q) & 1u) && kk >= TkA) {
        mxA = kk > mxA ? kk : mxA;
        int p = atomicAdd(&ctrl[1], 1);
        if (p < CA_CAP) { cA[p].x = kk; cA[p].y = j; }
      }
    }
  }
#pragma unroll
  for (int o = 32; o; o >>= 1) {
    unsigned a = __shfl_xor(mxM, o); mxM = a > mxM ? a : mxM;
    unsigned b = __shfl_xor(mxA, o); mxA = b > mxA ? b : mxA;
  }
  if (lane == 0) { atomicMax(&uctrl[10], mxM); atomicMax(&uctrl[11], mxA); }
  __syncthreads();
  int ccM = ctrl[0], ccA = ctrl[1];
  bool ok = (!mainOn || (ccM >= kmain && ccM <= CM_CAP)) &&
            (!auxOn  || (ccA >= kauxE && ccA <= CA_CAP));
  if (!ok) { if (t == 0) flags[r] = 1; return; }
  if (!auxOn) ccA = 0;
  if (!mainOn) ccM = 0;
  unsigned MxM = uctrl[10], MxA = uctrl[11];
  float sclM = 255.0f / fmaxf((float)(MxM - TkM) + 1.0f, 1.0f);
  float sclA = 255.0f / fmaxf((float)(MxA - TkA) + 1.0f, 1.0f);

  // ---- histogram rank (linear) ----
  for (int c = t; c < ccM; c += 1024) {
    int b = (int)((float)(cM[c].x - TkM) * sclM);
    b = b < 0 ? 0 : (b > 255 ? 255 : b);
    atomicAdd(&histM[b], 1);
  }
  for (int c = t; c < ccA; c += 1024) {
    int b = (int)((float)(cA[c].x - TkA) * sclA);
    b = b < 0 ? 0 : (b > 255 ? 255 : b);
    atomicAdd(&histA[b], 1);
  }
  __syncthreads();
  if (t == 0 && mainOn) {
    int above = 0, b = 0;
    for (int i = 255; i >= 0; --i) {
      if (above + histM[i] >= kmain) { b = i; break; }
      above += histM[i];
    }
    ctrl[12] = b; ctrl[13] = above;
  }
  if (t == 64 && auxOn) {
    int above = 0, b = 0;
    for (int i = 255; i >= 0; --i) {
      if (above + histA[i] >= kauxE) { b = i; break; }
      above += histA[i];
    }
    ctrl[14] = b; ctrl[15] = above;
  }
  __syncthreads();
  int bM = ctrl[12], aboveM = ctrl[13];
  int bA = ctrl[14], aboveA = ctrl[15];
  for (int c = t; c < ccM; c += 1024) {
    int b = (int)((float)(cM[c].x - TkM) * sclM);
    b = b < 0 ? 0 : (b > 255 ? 255 : b);
    if (b == bM) {
      int p = atomicAdd(&ctrl[16], 1);
      if (p < BB_CAP) bbM[p] = cM[c];
    }
  }
  for (int c = t; c < ccA; c += 1024) {
    int b = (int)((float)(cA[c].x - TkA) * sclA);
    b = b < 0 ? 0 : (b > 255 ? 255 : b);
    if (b == bA) {
      int p = atomicAdd(&ctrl[17], 1);
      if (p < BB_CAP) bbA[p] = cA[c];
    }
  }
  __syncthreads();
  int nbM = ctrl[16], nbA = ctrl[17];
  if ((mainOn && nbM > BB_CAP) || (auxOn && nbA > BB_CAP)) {
    if (t == 0) flags[r] = 1;
    return;
  }
  if (t == 0) flags[r] = 0;
  if (!mainOn) nbM = 0;
  if (!auxOn) nbA = 0;
  if (t < nbM) {
    uint2 e = bbM[t];
    int rank = 0;
    for (int qq = 0; qq < nbM; ++qq) {
      uint2 f = bbM[qq];
      rank += (f.x > e.x || (f.x == e.x && (int)f.y < (int)e.y)) ? 1 : 0;
    }
    if (rank == kmain - aboveM - 1) ctrl[2] = (int)e.x;
  }
  if (t >= 512 && t - 512 < nbA) {
    uint2 e = bbA[t - 512];
    int rank = 0;
    for (int qq = 0; qq < nbA; ++qq) {
      uint2 f = bbA[qq];
      rank += (f.x > e.x || (f.x == e.x && (int)f.y < (int)e.y)) ? 1 : 0;
    }
    if (rank == kauxE - aboveA - 1) ctrl[3] = (int)e.x;
  }
  __syncthreads();

  // ---- bands around kth value ----
  float VsM = keyinv((unsigned)ctrl[2]);
  float epsM = 1e-2f + 2e-3f * fabsf(VsM);
  unsigned KhiBM = mainOn ? fkey(VsM + epsM) : 0xFFFFFFFFu;
  unsigned KloBM = mainOn ? fkey(VsM - epsM) : 0xFFFFFFFFu;
  float VsA = keyinv((unsigned)ctrl[3]);
  float epsA = 1e-2f + 2e-3f * fabsf(VsA);
  unsigned KhiBA = auxOn ? fkey(VsA + epsA) : 0xFFFFFFFFu;
  unsigned KloBA = auxOn ? fkey(VsA - epsA) : 0xFFFFFFFFu;
  for (int c = t; c < ccM; c += 1024) {
    unsigned kk = cM[c].x;
    if (kk > KhiBM) atomicAdd(&ctrl[4], 1);
    else if (kk >= KloBM) {
      int p = atomicAdd(&ctrl[5], 1);
      if (p < BAND_CAP) biM[p] = (int)cM[c].y;
    }
  }
  for (int c = t; c < ccA; c += 1024) {
    unsigned kk = cA[c].x;
    if (kk > KhiBA) atomicAdd(&ctrl[6], 1);
    else if (kk >= KloBA) {
      int p = atomicAdd(&ctrl[7], 1);
      if (p < BAND_CAP) biA[p] = (int)cA[c].y;
    }
  }
  __syncthreads();
  int nAbM = ctrl[4], bcM = ctrl[5] < BAND_CAP ? ctrl[5] : BAND_CAP;
  int nAbA = ctrl[6], bcA = ctrl[7] < BAND_CAP ? ctrl[7] : BAND_CAP;
  if (!mainOn) bcM = 0;
  if (!auxOn) bcA = 0;
  int needBM = kmain - nAbM; if (needBM < 0) needBM = 0; if (needBM > bcM) needBM = bcM;
  int needBA = kauxE - nAbA; if (needBA < 0) needBA = 0; if (needBA > bcA) needBA = bcA;

  // ---- f64 band dots (wave-per-member) ----
  {
    const float* xr = x + (size_t)r * NIN;
    float xb[NIN / 64];
#pragma unroll
    for (int jj = 0; jj < NIN / 64; ++jj) {
      int col = lane + 64 * jj;
      xb[jj] = xr[col] - bvec[col];
    }
    int tot = bcM + bcA;
    for (int m = wave; m < tot; m += 16) {
      int j = (m < bcM) ? biM[m] : biA[m - bcM];
      const float* wr = We + (size_t)j * NIN;
      double s = 0.0;
#pragma unroll
      for (int jj = 0; jj < NIN / 64; ++jj)
        s += (double)xb[jj] * (double)wr[lane + 64 * jj];
#pragma unroll
      for (int o = 32; o; o >>= 1) s += __shfl_xor(s, o);
      if (lane == 0) {
        if (m < bcM) bvM[m] = s + (double)be[j];
        else bvA[m - bcM] = s + (double)be[j];
      }
    }
  }
  __syncthreads();
  if (t < bcM) {
    double vi = bvM[t]; int ii = biM[t];
    double tie = fabs(vi) * 4e-8 + 1e-12;
    int rank = 0;
    for (int qq = 0; qq < bcM; ++qq) {
      double d = bvM[qq] - vi;
      rank += ((fabs(d) <= tie) ? (biM[qq] < ii) : (d > 0.0)) ? 1 : 0;
    }
    bsM[t] = (rank < needBM) ? 1 : 0;
  }
  if (t >= 512 && t - 512 < bcA) {
    int tt = t - 512;
    double vi = bvA[tt]; int ii = biA[tt];
    double tie = fabs(vi) * 4e-8 + 1e-12;
    int rank = 0;
    for (int qq = 0; qq < bcA; ++qq) {
      double d = bvA[qq] - vi;
      rank += ((fabs(d) <= tie) ? (biA[qq] < ii) : (d > 0.0)) ? 1 : 0;
    }
    bsA[tt] = (rank < needBA) ? 1 : 0;
  }
  __syncthreads();

  // ---- selected lists from candidates ----
  for (int c = t; c < ccM; c += 1024) {
    unsigned kk = cM[c].x; int j = (int)cM[c].y;
    bool sel = kk > KhiBM;
    if (!sel && kk >= KloBM) {
      for (int m2 = 0; m2 < bcM; ++m2)
        if (biM[m2] == j) { sel = bsM[m2] != 0; break; }
    }
    float v = keyinv(kk);
    if (sel && v != 0.0f) {
      int p = atomicAdd(&ctrl[8], 1);
      if (p < MAIN_CAP) { mIdxG[r * MAIN_CAP + p] = j; mValG[r * MAIN_CAP + p] = v; }
    }
  }
  for (int c = t; c < ccA; c += 1024) {
    unsigned kk = cA[c].x; int j = (int)cA[c].y;
    bool sel = kk > KhiBA;
    if (!sel && kk >= KloBA) {
      for (int m2 = 0; m2 < bcA; ++m2)
        if (biA[m2] == j) { sel = bsA[m2] != 0; break; }
    }
    float v = keyinv(kk);
    if (sel && v != 0.0f) {
      int p = atomicAdd(&ctrl[9], 1);
      if (p < AUX_CAP) { aIdxG[r * AUX_CAP + p] = j; aValG[r * AUX_CAP + p] = v; }
    }
  }
  __syncthreads();
  if (t == 0) {
    cnts[2 * r] = ctrl[8] < MAIN_CAP ? ctrl[8] : MAIN_CAP;
    cnts[2 * r + 1] = auxOn ? (ctrl[9] < AUX_CAP ? ctrl[9] : AUX_CAP) : 0;
  }

  // ---- scan 3: fused dense alpha/mask emit (read-then-write; mask aliases apre) ----
  {
    float4* arow = (float4*)(alpha + (size_t)r * NLAT);
    float4* mrow = (float4*)(mask + (size_t)r * NLAT);
#pragma unroll
    for (int i = 0; i < GRP; ++i) {
      int g = t + SELT * i;
      uint4 rv = rowp[g];
      float vs[4] = {__uint_as_float(rv.x), __uint_as_float(rv.y),
                     __uint_as_float(rv.z), __uint_as_float(rv.w)};
      float av[4], mv[4];
#pragma unroll
      for (int q = 0; q < 4; ++q) {
        float v = vs[q];
        unsigned kk = fkey(v);
        int j = 4 * g + q;
        bool sel = kk > KhiBM;
        if (!sel && kk >= KloBM) {
          for (int m2 = 0; m2 < bcM; ++m2)
            if (biM[m2] == j) { sel = bsM[m2] != 0; break; }
        }
        av[q] = sel ? v : 0.0f;
        mv[q] = (sel && v != 0.0f) ? 1.0f : 0.0f;
      }
      arow[g] = make_float4(av[0], av[1], av[2], av[3]);
      mrow[g] = make_float4(mv[0], mv[1], mv[2], mv[3]);
    }
  }
}

// ------------- fallback: proven select12, gated on flags ----
__global__ __launch_bounds__(SELT) void k_selectFB(
    const float* apre, const float* __restrict__ x,
    const float* __restrict__ bvec, const float* __restrict__ We,
    const float* __restrict__ be, const unsigned* __restrict__ dbits,
    const int* __restrict__ kptr, const int* __restrict__ akptr,
    float* __restrict__ alpha, float* mask,
    int* __restrict__ cnts, int* __restrict__ mIdxG, float* __restrict__ mValG,
    int* __restrict__ aIdxG, float* __restrict__ aValG,
    const int* __restrict__ flags) {
  if (flags[blockIdx.x] == 0) return;
  extern __shared__ char smem[];
  uint2*    keys2 = (uint2*)(smem + OFF_K16);
  float*    redF  = (float*)(smem + OFF_REDF);
  int*      redI  = (int*)(smem + OFF_REDI);
  int*      ctrl  = (int*)(smem + OFF_CTRL);
  float*    ctrlF = (float*)(smem + OFF_CTRL);
  int*      pcnt  = (int*)(smem + OFF_PCNT);
  unsigned* ckM   = (unsigned*)(smem + OFF_CKM);
  int*      ciM   = (int*)(smem + OFF_CIM);
  unsigned* ckA   = (unsigned*)(smem + OFF_CKA);
  int*      ciA   = (int*)(smem + OFF_CIA);
  int*      biM   = (int*)(smem + OFF_BIM);
  int*      biA   = (int*)(smem + OFF_BIA);
  double*   bvM   = (double*)(smem + OFF_BVM);
  double*   bvA   = (double*)(smem + OFF_BVA);
  unsigned char* bsM = (unsigned char*)(smem + OFF_BSM);
  unsigned char* bsA = (unsigned char*)(smem + OFF_BSA);

  const int t = threadIdx.x;
  const int r = blockIdx.x;
  const int lane = t & 63, wave = t >> 6;

  if (t < 96) pcnt[t] = 0;
  else if (t < 108) ctrl[t - 96] = 0;

  const uint4* rowp = (const uint4*)(apre + (size_t)r * NLAT);
  const float* rowf = apre + (size_t)r * NLAT;
  unsigned dm = 0;
  float s1 = 0.f, s2 = 0.f;
  float vmxA = -INFINITY, vmnA = INFINITY, vmxD = -INFINITY, vmnD = INFINITY;
#pragma unroll
  for (int i = 0; i < GRP; ++i) {
    int g = t + SELT * i;
    uint4 rv = rowp[g];
    unsigned nb = (dbits[g >> 3] >> ((g & 7) * 4)) & 0xFu;
    dm |= nb << (4 * i);
    float vs[4] = {__uint_as_float(rv.x), __uint_as_float(rv.y),
                   __uint_as_float(rv.z), __uint_as_float(rv.w)};
    unsigned k16[4];
#pragma unroll
    for (int q = 0; q < 4; ++q) {
      float v = vs[q];
      k16[q] = fkey(v) >> 16;
      s1 += v; s2 += v * v;
      vmxA = fmaxf(vmxA, v); vmnA = fminf(vmnA, v);
      if ((nb >> q) & 1u) { vmxD = fmaxf(vmxD, v); vmnD = fminf(vmnD, v); }
    }
    uint2 kp2;
    kp2.x = k16[0] | (k16[1] << 16);
    kp2.y = k16[2] | (k16[3] << 16);
    keys2[g] = kp2;
  }
  int nd = __popc(dm & 0xFFFFFFu);
#pragma unroll
  for (int o = 32; o; o >>= 1) {
    s1 += __shfl_xor(s1, o); s2 += __shfl_xor(s2, o);
    vmxA = fmaxf(vmxA, __shfl_xor(vmxA, o)); vmnA = fminf(vmnA, __shfl_xor(vmnA, o));
    vmxD = fmaxf(vmxD, __shfl_xor(vmxD, o)); vmnD = fminf(vmnD, __shfl_xor(vmnD, o));
    nd += __shfl_xor(nd, o);
  }
  if (lane == 0) {
    float* rf = redF + wave * 8;
    rf[0] = s1; rf[1] = s2; rf[2] = vmxA; rf[3] = vmnA; rf[4] = vmxD; rf[5] = vmnD;
    redI[wave] = nd;
  }
  __syncthreads();
  if (wave == 0) {
    float a0 = 0.f, a1 = 0.f, a2 = -INFINITY, a3 = INFINITY, a4 = -INFINITY, a5 = INFINITY;
    int a6 = 0;
    if (lane < 16) {
      const float* rf = redF + lane * 8;
      a0 = rf[0]; a1 = rf[1]; a2 = rf[2]; a3 = rf[3]; a4 = rf[4]; a5 = rf[5];
      a6 = redI[lane];
    }
#pragma unroll
    for (int o = 32; o; o >>= 1) {
      a0 += __shfl_xor(a0, o); a1 += __shfl_xor(a1, o);
      a2 = fmaxf(a2, __shfl_xor(a2, o)); a3 = fminf(a3, __shfl_xor(a3, o));
      a4 = fmaxf(a4, __shfl_xor(a4, o)); a5 = fminf(a5, __shfl_xor(a5, o));
      a6 += __shfl_xor(a6, o);
    }
    if (lane == 0) {
      float mu = a0 / (float)NLAT;
      float var = fmaxf(a1 / (float)NLAT - mu * mu, 1e-20f);
      ctrlF[16] = mu; ctrlF[17] = sqrtf(var);
      ctrlF[18] = a3; ctrlF[19] = a2;
      ctrlF[20] = a5; ctrlF[21] = a4;
      ctrl[22] = a6;
    }
  }
  __syncthreads();

  int kmain = kptr[0]; if (kmain > MAIN_CAP) kmain = MAIN_CAP;
  int kaux  = akptr[0]; if (kaux > AUX_CAP)  kaux  = AUX_CAP;
  const float mu = ctrlF[16], sg = ctrlF[17];
  const int ndead = ctrl[22];
  int kauxE = kaux > ndead ? ndead : kaux;
  const bool mainOn = (kmain > 0);
  const bool auxOn  = (kauxE > 0);

  unsigned TloM = fkey(ctrlF[18]) >> 16, ThiM = (fkey(ctrlF[19]) >> 16) + 1u;
  int cLoM = NLAT, cHiM = 0;
  unsigned TloA = 0u, ThiA = 2u;
  int cLoA = 0, cHiA = 0;
  if (auxOn) { TloA = fkey(ctrlF[20]) >> 16; ThiA = (fkey(ctrlF[21]) >> 16) + 1u; cLoA = ndead; }

  for (int it = 0; it < 16; ++it) {
    bool actM = mainOn && (cLoM - cHiM) > (CAND_CAP - 8) && (ThiM - TloM) > 1u;
    bool actA = auxOn  && (cLoA - cHiA) > (CAND_CAP - 8) && (ThiA - TloA) > 1u;
    if (!actM && !actA) break;
    unsigned TM1 = TloM + 1u, TM2 = TM1, TM3 = TM1;
    unsigned TA1 = TloA + 1u, TA2 = TA1, TA3 = TA1;
    if (actM) {
      unsigned lo1 = TloM + 1u, hi1 = ThiM - 1u;
      if (it == 0) {
        float fn = (float)NLAT;
        TM1 = fkey(mu + sg * zup(4.f * kmain / fn)) >> 16;
        TM2 = fkey(mu + sg * zup((float)kmain / fn)) >> 16;
        TM3 = fkey(mu + sg * zup(0.25f * kmain / fn)) >> 16;
      } else {
        float vlo = keyinv(TloM << 16), vhi = keyinv((ThiM << 16) - 1u);
        TM1 = fkey(0.75f * vlo + 0.25f * vhi) >> 16;
        TM2 = fkey(0.50f * vlo + 0.50f * vhi) >> 16;
        TM3 = fkey(0.25f * vlo + 0.75f * vhi) >> 16;
      }
      TM1 = TM1 < lo1 ? lo1 : (TM1 > hi1 ? hi1 : TM1);
      TM2 = TM2 < TM1 ? TM1 : (TM2 > hi1 ? hi1 : TM2);
      TM3 = TM3 < TM2 ? TM2 : (TM3 > hi1 ? hi1 : TM3);
    }
    if (actA) {
      unsigned lo1 = TloA + 1u, hi1 = ThiA - 1u;
      if (it == 0) {
        float fn = (float)ndead;
        TA1 = fkey(mu + sg * zup(4.f * kauxE / fn)) >> 16;
        TA2 = fkey(mu + sg * zup((float)kauxE / fn)) >> 16;
        TA3 = fkey(mu + sg * zup(0.25f * kauxE / fn)) >> 16;
      } else {
        float vlo = keyinv(TloA << 16), vhi = keyinv((ThiA << 16) - 1u);
        TA1 = fkey(0.75f * vlo + 0.25f * vhi) >> 16;
        TA2 = fkey(0.50f * vlo + 0.50f * vhi) >> 16;
        TA3 = fkey(0.25f * vlo + 0.75f * vhi) >> 16;
      }
      TA1 = TA1 < lo1 ? lo1 : (TA1 > hi1 ? hi1 : TA1);
      TA2 = TA2 < TA1 ? TA1 : (TA2 > hi1 ? hi1 : TA2);
      TA3 = TA3 < TA2 ? TA2 : (TA3 > hi1 ? hi1 : TA3);
    }
    int cm1 = 0, cm2 = 0, cm3 = 0, ca1 = 0, ca2 = 0, ca3 = 0;
#pragma unroll
    for (int i = 0; i < GRP; ++i) {
      uint2 kv = keys2[t + SELT * i];
      unsigned nb = (dm >> (4 * i)) & 0xFu;
      unsigned ks[4] = {kv.x & 0xFFFFu, kv.x >> 16, kv.y & 0xFFFFu, kv.y >> 16};
#pragma unroll
      for (int q = 0; q < 4; ++q) {
        unsigned kk = ks[q];
        cm1 += (kk >= TM1); cm2 += (kk >= TM2); cm3 += (kk >= TM3);
        if ((nb >> q) & 1u) { ca1 += (kk >= TA1); ca2 += (kk >= TA2); ca3 += (kk >= TA3); }
      }
    }
#pragma unroll
    for (int o = 32; o; o >>= 1) {
      cm1 += __shfl_xor(cm1, o); cm2 += __shfl_xor(cm2, o); cm3 += __shfl_xor(cm3, o);
      ca1 += __shfl_xor(ca1, o); ca2 += __shfl_xor(ca2, o); ca3 += __shfl_xor(ca3, o);
    }
    if (lane == 0) {
      int* pc = pcnt + it * 6;
      atomicAdd(&pc[0], cm1); atomicAdd(&pc[1], cm2); atomicAdd(&pc[2], cm3);
      atomicAdd(&pc[3], ca1); atomicAdd(&pc[4], ca2); atomicAdd(&pc[5], ca3);
    }
    __syncthreads();
    const int* pc = pcnt + it * 6;
    int CM1 = pc[0], CM2 = pc[1], CM3 = pc[2];
    int CA1 = pc[3], CA2 = pc[4], CA3 = pc[5];
    if (actM) {
      if (CM3 >= kmain)      { TloM = TM3; cLoM = CM3; }
      else if (CM2 >= kmain) { TloM = TM2; cLoM = CM2; ThiM = TM3; cHiM = CM3; }
      else if (CM1 >= kmain) { TloM = TM1; cLoM = CM1; ThiM = TM2; cHiM = CM2; }
      else                   { ThiM = TM1; cHiM = CM1; }
    }
    if (actA) {
      if (CA3 >= kauxE)      { TloA = TA3; cLoA = CA3; }
      else if (CA2 >= kauxE) { TloA = TA2; cLoA = CA2; ThiA = TA3; cHiA = CA3; }
      else if (CA1 >= kauxE) { TloA = TA1; cLoA = CA1; ThiA = TA2; cHiA = CA2; }
      else                   { ThiA = TA1; cHiA = CA1; }
    }
  }

#pragma unroll
  for (int i = 0; i < GRP; ++i) {
    int g = t + SELT * i;
    uint2 kv = keys2[g];
    unsigned nb = (dm >> (4 * i)) & 0xFu;
    unsigned ks[4] = {kv.x & 0xFFFFu, kv.x >> 16, kv.y & 0xFFFFu, kv.y >> 16};
#pragma unroll
    for (int q = 0; q < 4; ++q) {
      unsigned kk = ks[q];
      int j = 4 * g + q;
      if (mainOn && kk >= TloM && kk < ThiM) {
        int p = atomicAdd(&ctrl[0], 1);
        if (p < CAND_CAP) { ckM[p] = fkey(rowf[j]); ciM[p] = j; }
      }
      if (auxOn && ((nb >> q) & 1u) && kk >= TloA && kk < ThiA) {
        int p = atomicAdd(&ctrl[1], 1);
        if (p < CAND_CAP) { ckA[p] = fkey(rowf[j]); ciA[p] = j; }
      }
    }
  }
  __syncthreads();
  int ccM = ctrl[0] < CAND_CAP ? ctrl[0] : CAND_CAP;
  int ccA = ctrl[1] < CAND_CAP ? ctrl[1] : CAND_CAP;
  int needM = kmain - cHiM; if (needM < 1) needM = 1; if (needM > ccM) needM = ccM;
  int needA = kauxE - cHiA; if (needA < 1) needA = 1; if (needA > ccA) needA = ccA;

  if (t < ccM) {
    unsigned ki = ckM[t]; int ii = ciM[t];
    int rank = 0;
    for (int qq = 0; qq < ccM; ++qq) {
      unsigned kq = ckM[qq];
      rank += (kq > ki || (kq == ki && ciM[qq] < ii)) ? 1 : 0;
    }
    if (rank == needM - 1) ctrl[2] = (int)ki;
  } else if (t >= 512 && t - 512 < ccA) {
    int tt = t - 512;
    unsigned ki = ckA[tt]; int ii = ciA[tt];
    int rank = 0;
    for (int qq = 0; qq < ccA; ++qq) {
      unsigned kq = ckA[qq];
      rank += (kq > ki || (kq == ki && ciA[qq] < ii)) ? 1 : 0;
    }
    if (rank == needA - 1) ctrl[3] = (int)ki;
  }
  __syncthreads();

  float VsM = keyinv((unsigned)ctrl[2]);
  float epsM = 1e-2f + 2e-3f * fabsf(VsM);
  unsigned KhiBM = mainOn ? fkey(VsM + epsM) : 0xFFFFFFFFu;
  unsigned KloBM = mainOn ? fkey(VsM - epsM) : 0xFFFFFFFFu;
  float VsA = keyinv((unsigned)ctrl[3]);
  float epsA = 1e-2f + 2e-3f * fabsf(VsA);
  unsigned KhiBA = auxOn ? fkey(VsA + epsA) : 0xFFFFFFFFu;
  unsigned KloBA = auxOn ? fkey(VsA - epsA) : 0xFFFFFFFFu;
  unsigned KhiBM16 = KhiBM >> 16, KloBM16 = KloBM >> 16;
  unsigned KhiBA16 = KhiBA >> 16, KloBA16 = KloBA >> 16;
  int abvM = 0, abvA = 0;
#pragma unroll
  for (int i = 0; i < GRP; ++i) {
    int g = t + SELT * i;
    uint2 kv = keys2[g];
    unsigned nb = (dm >> (4 * i)) & 0xFu;
    unsigned ks[4] = {kv.x & 0xFFFFu, kv.x >> 16, kv.y & 0xFFFFu, kv.y >> 16};
#pragma unroll
    for (int q = 0; q < 4; ++q) {
      unsigned kk = ks[q];
      int j = 4 * g + q;
      if (mainOn) {
        if (kk > KhiBM16) ++abvM;
        else if (kk >= KloBM16) {
          unsigned kf = fkey(rowf[j]);
          if (kf > KhiBM) ++abvM;
          else if (kf >= KloBM) {
            int p = atomicAdd(&ctrl[5], 1);
            if (p < BAND_CAP) biM[p] = j;
          }
        }
      }
      if (auxOn && ((nb >> q) & 1u)) {
        if (kk > KhiBA16) ++abvA;
        else if (kk >= KloBA16) {
          unsigned kf = fkey(rowf[j]);
          if (kf > KhiBA) ++abvA;
          else if (kf >= KloBA) {
            int p = atomicAdd(&ctrl[7], 1);
            if (p < BAND_CAP) biA[p] = j;
          }
        }
      }
    }
  }
#pragma unroll
  for (int o = 32; o; o >>= 1) { abvM += __shfl_xor(abvM, o); abvA += __shfl_xor(abvA, o); }
  if (lane == 0) { atomicAdd(&ctrl[4], abvM); atomicAdd(&ctrl[6], abvA); }
  __syncthreads();
  int nAbM = ctrl[4], bcM = ctrl[5] < BAND_CAP ? ctrl[5] : BAND_CAP;
  int nAbA = ctrl[6], bcA = auxOn ? (ctrl[7] < BAND_CAP ? ctrl[7] : BAND_CAP) : 0;
  if (!mainOn) bcM = 0;
  int needBM = kmain - nAbM; if (needBM < 0) needBM = 0; if (needBM > bcM) needBM = bcM;
  int needBA = kauxE - nAbA; if (needBA < 0) needBA = 0; if (needBA > bcA) needBA = bcA;

  {
    const float* xr = x + (size_t)r * NIN;
    float xb[NIN / 64];
#pragma unroll
    for (int jj = 0; jj < NIN / 64; ++jj) {
      int col = lane + 64 * jj;
      xb[jj] = xr[col] - bvec[col];
    }
    int tot = bcM + bcA;
    for (int m = wave; m < tot; m += 16) {
      int j = (m < bcM) ? biM[m] : biA[m - bcM];
      const float* wr = We + (size_t)j * NIN;
      double s = 0.0;
#pragma unroll
      for (int jj = 0; jj < NIN / 64; ++jj)
        s += (double)xb[jj] * (double)wr[lane + 64 * jj];
#pragma unroll
      for (int o = 32; o; o >>= 1) s += __shfl_xor(s, o);
      if (lane == 0) {
        if (m < bcM) bvM[m] = s + (double)be[j];
        else bvA[m - bcM] = s + (double)be[j];
      }
    }
  }
  __syncthreads();
  if (t < bcM) {
    double vi = bvM[t]; int ii = biM[t];
    double tie = fabs(vi) * 4e-8 + 1e-12;
    int rank = 0;
    for (int qq = 0; qq < bcM; ++qq) {
      double d = bvM[qq] - vi;
      rank += ((fabs(d) <= tie) ? (biM[qq] < ii) : (d > 0.0)) ? 1 : 0;
    }
    bsM[t] = (rank < needBM) ? 1 : 0;
  } else if (t >= 512 && t - 512 < bcA) {
    int tt = t - 512;
    double vi = bvA[tt]; int ii = biA[tt];
    double tie = fabs(vi) * 4e-8 + 1e-12;
    int rank = 0;
    for (int qq = 0; qq < bcA; ++qq) {
      double d = bvA[qq] - vi;
      rank += ((fabs(d) <= tie) ? (biA[qq] < ii) : (d > 0.0)) ? 1 : 0;
    }
    bsA[tt] = (rank < needBA) ? 1 : 0;
  }
  __syncthreads();

  {
    float4* arow = (float4*)(alpha + (size_t)r * NLAT);
    float4* mrow = (float4*)(mask + (size_t)r * NLAT);
#pragma unroll
    for (int i = 0; i < GRP; ++i) {
      int g = t + SELT * i;
      uint4 rv = rowp[g];
      unsigned nb = (dm >> (4 * i)) & 0xFu;
      float vs[4] = {__uint_as_float(rv.x), __uint_as_float(rv.y),
                     __uint_as_float(rv.z), __uint_as_float(rv.w)};
      float av[4], mv[4];
#pragma unroll
      for (int q = 0; q < 4; ++q) {
        float v = vs[q];
        unsigned kk = fkey(v);
        int j = 4 * g + q;
        bool selM = mainOn && (kk > KhiBM);
        if (mainOn && !selM && kk >= KloBM) {
          for (int m2 = 0; m2 < bcM; ++m2)
            if (biM[m2] == j) { selM = bsM[m2] != 0; break; }
        }
        bool nz = selM && (v != 0.0f);
        av[q] = selM ? v : 0.0f;
        mv[q] = nz ? 1.0f : 0.0f;
        if (nz) {
          int p = atomicAdd(&ctrl[8], 1);
          if (p < MAIN_CAP) { mIdxG[r * MAIN_CAP + p] = j; mValG[r * MAIN_CAP + p] = v; }
        }
        if (auxOn && ((nb >> q) & 1u)) {
          bool selA = kk > KhiBA;
          if (!selA && kk >= KloBA) {
            for (int m2 = 0; m2 < bcA; ++m2)
              if (biA[m2] == j) { selA = bsA[m2] != 0; break; }
          }
          if (selA && v != 0.0f) {
            int p = atomicAdd(&ctrl[9], 1);
            if (p < AUX_CAP) { aIdxG[r * AUX_CAP + p] = j; aValG[r * AUX_CAP + p] = v; }
          }
        }
      }
      arow[g] = make_float4(av[0], av[1], av[2], av[3]);
      mrow[g] = make_float4(mv[0], mv[1], mv[2], mv[3]);
    }
  }
  __syncthreads();
  if (t == 0) {
    cnts[2 * r] = ctrl[8] < MAIN_CAP ? ctrl[8] : MAIN_CAP;
    cnts[2 * r + 1] = auxOn ? (ctrl[9] < AUX_CAP ? ctrl[9] : AUX_CAP) : 0;
  }
}

// ------------- decode ----
__global__ __launch_bounds__(256) void k_decode(
    const int* __restrict__ cnts, const int* __restrict__ mIdxG,
    const float* __restrict__ mValG, const int* __restrict__ aIdxG,
    const float* __restrict__ aValG, const float* __restrict__ bvec,
    const __bf16* __restrict__ Wt, const float* __restrict__ Wd,
    float* __restrict__ xhat, float* __restrict__ auxo) {
  const int r = blockIdx.x, t = threadIdx.x;
  __shared__ int sMi[MAIN_CAP];
  __shared__ float sMv[MAIN_CAP];
  __shared__ int sAi[AUX_CAP];
  __shared__ float sAv[AUX_CAP];
  int kc = cnts[2 * r], ac = cnts[2 * r + 1];
  if (t < MAIN_CAP && t < kc) { sMi[t] = mIdxG[r * MAIN_CAP + t]; sMv[t] = mValG[r * MAIN_CAP + t]; }
  for (int i = t; i < ac; i += 256) { sAi[i] = aIdxG[r * AUX_CAP + i]; sAv[i] = aValG[r * AUX_CAP + i]; }
  __syncthreads();

  float o0 = 0.f, o1 = 0.f, o2 = 0.f;
  float a0 = 0.f, a1 = 0.f, a2 = 0.f;
  if (Wt) {
    int i = 0;
    for (; i + 4 <= kc; i += 4) {
      int i0 = sMi[i], i1 = sMi[i + 1], i2 = sMi[i + 2], i3 = sMi[i + 3];
      float v0 = sMv[i], v1 = sMv[i + 1], v2 = sMv[i + 2], v3 = sMv[i + 3];
      const __bf16* p0 = Wt + (size_t)i0 * NIN;
      const __bf16* p1 = Wt + (size_t)i1 * NIN;
      const __bf16* p2 = Wt + (size_t)i2 * NIN;
      const __bf16* p3 = Wt + (size_t)i3 * NIN;
      float w00 = p0[t], w01 = p0[t + 256], w02 = p0[t + 512];
      float w10 = p1[t], w11 = p1[t + 256], w12 = p1[t + 512];
      float w20 = p2[t], w21 = p2[t + 256], w22 = p2[t + 512];
      float w30 = p3[t], w31 = p3[t + 256], w32 = p3[t + 512];
      o0 = fmaf(v0, w00, o0); o1 = fmaf(v0, w01, o1); o2 = fmaf(v0, w02, o2);
      o0 = fmaf(v1, w10, o0); o1 = fmaf(v1, w11, o1); o2 = fmaf(v1, w12, o2);
      o0 = fmaf(v2, w20, o0); o1 = fmaf(v2, w21, o1); o2 = fmaf(v2, w22, o2);
      o0 = fmaf(v3, w30, o0); o1 = fmaf(v3, w31, o1); o2 = fmaf(v3, w32, o2);
    }
    for (; i < kc; ++i) {
      const __bf16* p = Wt + (size_t)sMi[i] * NIN;
      float v = sMv[i];
      o0 = fmaf(v, (float)p[t], o0);
      o1 = fmaf(v, (float)p[t + 256], o1);
      o2 = fmaf(v, (float)p[t + 512], o2);
    }
    i = 0;
    for (; i + 4 <= ac; i += 4) {
      int i0 = sAi[i], i1 = sAi[i + 1], i2 = sAi[i + 2], i3 = sAi[i + 3];
      float v0 = sAv[i], v1 = sAv[i + 1], v2 = sAv[i + 2], v3 = sAv[i + 3];
      const __bf16* p0 = Wt + (size_t)i0 * NIN;
      const __bf16* p1 = Wt + (size_t)i1 * NIN;
      const __bf16* p2 = Wt + (size_t)i2 * NIN;
      const __bf16* p3 = Wt + (size_t)i3 * NIN;
      float w00 = p0[t], w01 = p0[t + 256], w02 = p0[t + 512];
      float w10 = p1[t], w11 = p1[t + 256], w12 = p1[t + 512];
      float w20 = p2[t], w21 = p2[t + 256], w22 = p2[t + 512];
      float w30 = p3[t], w31 = p3[t + 256], w32 = p3[t + 512];
      a0 = fmaf(v0, w00, a0); a1 = fmaf(v0, w01, a1); a2 = fmaf(v0, w02, a2);
      a0 = fmaf(v1, w10, a0); a1 = fmaf(v1, w11, a1); a2 = fmaf(v1, w12, a2);
      a0 = fmaf(v2, w20, a0); a1 = fmaf(v2, w21, a1); a2 = fmaf(v2, w22, a2);
      a0 = fmaf(v3, w30, a0); a1 = fmaf(v3, w31, a1); a2 = fmaf(v3, w32, a2);
    }
    for (; i < ac; ++i) {
      const __bf16* p = Wt + (size_t)sAi[i] * NIN;
      float v = sAv[i];
      a0 = fmaf(v, (float)p[t], a0);
      a1 = fmaf(v, (float)p[t + 256], a1);
      a2 = fmaf(v, (float)p[t + 512], a2);
    }
  } else {
    for (int i = 0; i < kc; ++i) {
      float v = sMv[i]; int ix = sMi[i];
      o0 = fmaf(v, Wd[(size_t)t * NLAT + ix], o0);
      o1 = fmaf(v, Wd[(size_t)(t + 256) * NLAT + ix], o1);
      o2 = fmaf(v, Wd[(size_t)(t + 512) * NLAT + ix], o2);
    }
    for (int i = 0; i < ac; ++i) {
      float v = sAv[i]; int ix = sAi[i];
      a0 = fmaf(v, Wd[(size_t)t * NLAT + ix], a0);
      a1 = fmaf(v, Wd[(size_t)(t + 256) * NLAT + ix], a1);
      a2 = fmaf(v, Wd[(size_t)(t + 512) * NLAT + ix], a2);
    }
  }
  float b0 = bvec[t], b1 = bvec[t + 256], b2 = bvec[t + 512];
  xhat[(size_t)r * NIN + t] = o0 + b0;
  xhat[(size_t)r * NIN + t + 256] = o1 + b1;
  xhat[(size_t)r * NIN + t + 512] = o2 + b2;
  auxo[(size_t)r * NIN + t] = a0 + b0;
  auxo[(size_t)r * NIN + t + 256] = a1 + b1;
  auxo[(size_t)r * NIN + t + 512] = a2 + b2;
}

extern "C" void kernel_launch(void* const* d_in, const int* in_sizes, int n_in,
                              void* d_out, int out_size, void* d_ws, size_t ws_size,
                              hipStream_t stream) {
  const float* x  = (const float*)d_in[0];
  const float* bv = (const float*)d_in[1];
  const float* We = (const float*)d_in[2];
  const float* be = (const float*)d_in[3];
  const float* Wd = (const float*)d_in[4];
  const int* miss = (const int*)d_in[5];
  const int* kp   = (const int*)d_in[6];
  const int* akp  = (const int*)d_in[7];

  float* out   = (float*)d_out;
  float* xhat  = out;
  float* alpha = out + (size_t)3145728;
  float* apre  = out + (size_t)103809024;
  float* auxo  = out + (size_t)204472320;

  char* wsb = (char*)d_ws;
  size_t o = 0;
  unsigned* dbits = (unsigned*)(wsb + o); o += 65536;
  int*   cnts  = (int*)(wsb + o); o += 65536;
  int*   mIdxG = (int*)(wsb + o); o += (size_t)NB * MAIN_CAP * 4;
  float* mValG = (float*)(wsb + o); o += (size_t)NB * MAIN_CAP * 4;
  int*   aIdxG = (int*)(wsb + o); o += (size_t)NB * AUX_CAP * 4;
  float* aValG = (float*)(wsb + o); o += (size_t)NB * AUX_CAP * 4;
  int*   flags = (int*)(wsb + o); o += 65536;
  int*   ndead = (int*)(wsb + o); o += 65536;
  size_t offWt = o;
  size_t offA2 = offWt + (size_t)NLAT * NIN * 2;
  size_t offB2 = offA2 + (size_t)NB * K2 * 2;
  size_t needFull = offB2 + (size_t)NLAT * K2 * 2;
  bool haveWt   = ws_size >= offA2;
  bool haveFull = ws_size >= needFull;
  __bf16* Wt = haveWt ? (__bf16*)(wsb + offWt) : nullptr;
  __bf16* A2 = (__bf16*)(wsb + offA2);
  __bf16* B2 = (__bf16*)(wsb + offB2);

  k_deadbits<<<96, 256, 0, stream>>>(miss, dbits);
  k_ndead<<<1, 256, 0, stream>>>(dbits, ndead);
  if (haveFull) {
    k_pack_a<<<dim3(32, KT2), 256, 0, stream>>>(x, bv, A2);
    k_pack_b<<<dim3(192, KT2), 256, 0, stream>>>(We, B2);
  }
  if (haveWt)
    k_transpose<<<dim3(NLAT / 32, NIN / 32), dim3(32, 8), 0, stream>>>(Wd, Wt);

  if (haveFull)
    k_gemm_bf16<<<dim3(32, 192), 256, 0, stream>>>(A2, B2, be, apre);
  else
    k_encgemm_f32<<<dim3(NB / BM, NLAT / BN), 256, 0, stream>>>(x, bv, We, be, apre);

  k_select15<<<NB, 1024, 0, stream>>>(apre, x, bv, We, be, dbits, kp, akp, ndead,
                                      alpha, apre, cnts, mIdxG, mValG, aIdxG,
                                      aValG, flags);
  k_selectFB<<<NB, SELT, SMEM_SEL, stream>>>(apre, x, bv, We, be, dbits, kp, akp,
                                             alpha, apre, cnts, mIdxG, mValG,
                                             aIdxG, aValG, flags);
  k_decode<<<NB, 256, 0, stream>>>(cnts, mIdxG, mValG, aIdxG, aValG, bv,
                                   Wt, Wd, xhat, auxo);
}

// Round 16
// 1400.210 us; speedup vs baseline: 1.1996x; 1.1996x over previous
//
#include <hip/hip_runtime.h>
#include <math.h>

#define NB   4096
#define NIN  768
#define NLAT 24576
#define K2   768    // bf16 one-term: Ah x Bh (f64 band absorbs rounding)
#define KT2  12     // K2/64

// f32 fallback GEMM tiling
#define BM 128
#define BN 128
#define BK 16
#define LDT 132

#define CAND_CAP 512
#define BAND_CAP 160
#define MAIN_CAP 64
#define AUX_CAP  1024
#define SELT     1024
#define GRP      6

#define CM_CAP 768
#define CA_CAP 1536
#define BB_CAP 256
#define BPSTRIDE (BAND_CAP + 4)

// dynamic LDS layout for k_selectFB (16-bit-key fallback path)
#define OFF_K16  0
#define OFF_REDF 49152
#define OFF_CTRL 49664
#define OFF_PCNT 49792
#define OFF_CKM  50176
#define OFF_CIM  52224
#define OFF_CKA  54272
#define OFF_CIA  56320
#define OFF_BIM  58368
#define OFF_BIA  59008
#define OFF_BVM  59648
#define OFF_BVA  60928
#define OFF_BSM  62208
#define OFF_BSA  62368
#define OFF_REDI 62528
#define SMEM_SEL 62592

typedef __bf16 bf16x8 __attribute__((ext_vector_type(8)));
typedef float  f32x4  __attribute__((ext_vector_type(4)));

__device__ __forceinline__ unsigned fkey(float f) {
  unsigned u = __float_as_uint(f);
  return u ^ ((unsigned)((int)u >> 31) | 0x80000000u);  // monotone total order
}
__device__ __forceinline__ float keyinv(unsigned u) {
  unsigned s = (u & 0x80000000u) ? (u ^ 0x80000000u) : ~u;
  return __uint_as_float(s);
}
__device__ __forceinline__ float zup(float p) {
  p = fminf(fmaxf(p, 1e-7f), 0.5f);
  float t = sqrtf(-2.0f * logf(p));
  return t - (2.30753f + 0.27061f * t) / (1.0f + 0.99229f * t + 0.04481f * t * t);
}

#define GLOAD16(g, l) __builtin_amdgcn_global_load_lds( \
    (const __attribute__((address_space(1))) unsigned int*)(g), \
    (__attribute__((address_space(3))) unsigned int*)(l), 16, 0, 0)

// ---------------- dead bitset ----------------
__global__ __launch_bounds__(256) void k_deadbits(const int* __restrict__ miss,
                                                  unsigned* __restrict__ bits) {
  int j = blockIdx.x * 256 + threadIdx.x;
  unsigned long long b = __ballot(miss[j] >= 1);
  if ((threadIdx.x & 63) == 0) {
    int w = j >> 5;
    bits[w] = (unsigned)b;
    bits[w + 1] = (unsigned)(b >> 32);
  }
}

// ---------------- global dead count ----------------
__global__ __launch_bounds__(256) void k_ndead(const unsigned* __restrict__ bits,
                                               int* __restrict__ out) {
  __shared__ int w[4];
  int t = threadIdx.x;
  int c = 0;
  for (int i = t; i < NLAT / 32; i += 256) c += __popc(bits[i]);
#pragma unroll
  for (int o = 32; o; o >>= 1) c += __shfl_xor(c, o);
  if ((t & 63) == 0) w[t >> 6] = c;
  __syncthreads();
  if (t == 0) out[0] = w[0] + w[1] + w[2] + w[3];
}

// ---------------- W_dec -> Wt bf16 ----------------
__global__ __launch_bounds__(256) void k_transpose(const float* __restrict__ src,
                                                   __bf16* __restrict__ dst) {
  __shared__ float tile[32][33];
  int bx = blockIdx.x * 32;
  int by = blockIdx.y * 32;
  int tx = threadIdx.x, ty = threadIdx.y;
  for (int i = ty; i < 32; i += 8)
    tile[i][tx] = src[(size_t)(by + i) * NLAT + bx + tx];
  __syncthreads();
  for (int i = ty; i < 32; i += 8)
    dst[(size_t)(bx + i) * NIN + by + tx] = (__bf16)tile[tx][i];
}

// ---- packs (one-term bf16; K2=768, pre-swizzled LDS image) ----
__global__ __launch_bounds__(256) void k_pack_a(const float* __restrict__ x,
    const float* __restrict__ bvec, __bf16* __restrict__ A2) {
  const int mt = blockIdx.x, kt = blockIdx.y, t = threadIdx.x;
  __bf16* out = A2 + (((size_t)mt * KT2 + kt) << 13);
#pragma unroll
  for (int i = 0; i < 32; ++i) {
    int idx = i * 256 + t;
    int r = idx >> 6, c2 = idx & 63;
    int kk = c2 ^ ((r & 7) << 3);
    int k = kt * 64 + kk;
    float v = x[(size_t)(mt * 128 + r) * NIN + k] - bvec[k];
    out[idx] = (__bf16)v;
  }
}

__global__ __launch_bounds__(256) void k_pack_b(const float* __restrict__ We,
    __bf16* __restrict__ B2) {
  const int nt = blockIdx.x, kt = blockIdx.y, t = threadIdx.x;
  __bf16* out = B2 + (((size_t)nt * KT2 + kt) << 13);
#pragma unroll
  for (int i = 0; i < 32; ++i) {
    int idx = i * 256 + t;
    int r = idx >> 6, c2 = idx & 63;
    int kk = c2 ^ ((r & 7) << 3);
    int k = kt * 64 + kk;
    float v = We[(size_t)(nt * 128 + r) * NIN + k];
    out[idx] = (__bf16)v;
  }
}

// ---------------- bf16 MFMA GEMM (XCD-swizzled block map) ----------------
__global__ __launch_bounds__(256) void k_gemm_bf16(
    const __bf16* __restrict__ A2, const __bf16* __restrict__ B2,
    const float* __restrict__ be, float* __restrict__ apre) {
  __shared__ char sA[16384];
  __shared__ char sB[16384];
  const int t = threadIdx.x;
  const int lane = t & 63, wave = t >> 6;
  // bijective XCD swizzle: nwg=6144=8*768; each xcd gets a contiguous chunk
  int flat = blockIdx.y * 32 + blockIdx.x;
  int nf = (flat & 7) * 768 + (flat >> 3);
  const int mt = nf & 31, nt = nf >> 5;
  const int wm = wave >> 1, wn = wave & 1;

  int aoff[4][2], boff[4][2];
#pragma unroll
  for (int f = 0; f < 4; ++f) {
    int ra = wm * 64 + f * 16 + (lane & 15);
    int rb = wn * 64 + f * 16 + (lane & 15);
#pragma unroll
    for (int kk = 0; kk < 2; ++kk) {
      int c = kk * 64 + (lane >> 4) * 16;
      aoff[f][kk] = ra * 128 + (c ^ ((ra & 7) << 4));
      boff[f][kk] = rb * 128 + (c ^ ((rb & 7) << 4));
    }
  }
  f32x4 acc[4][4] = {};
  const char* gA = (const char*)(A2 + (((size_t)mt * KT2) << 13));
  const char* gB = (const char*)(B2 + (((size_t)nt * KT2) << 13));
  for (int kt = 0; kt < KT2; ++kt) {
    const char* tA = gA + ((size_t)kt << 14);
    const char* tB = gB + ((size_t)kt << 14);
#pragma unroll
    for (int i = 0; i < 4; ++i) {
      int chunk = (i * 4 + wave) * 1024;
      GLOAD16(tA + chunk + lane * 16, sA + chunk);
      GLOAD16(tB + chunk + lane * 16, sB + chunk);
    }
    __syncthreads();
#pragma unroll
    for (int kk = 0; kk < 2; ++kk) {
      bf16x8 a[4], b[4];
#pragma unroll
      for (int f = 0; f < 4; ++f) {
        a[f] = *(const bf16x8*)(sA + aoff[f][kk]);
        b[f] = *(const bf16x8*)(sB + boff[f][kk]);
      }
#pragma unroll
      for (int mi = 0; mi < 4; ++mi)
#pragma unroll
        for (int ni = 0; ni < 4; ++ni)
          acc[mi][ni] = __builtin_amdgcn_mfma_f32_16x16x32_bf16(a[mi], b[ni], acc[mi][ni], 0, 0, 0);
    }
    __syncthreads();
  }
  const int m0 = mt * 128 + wm * 64, n0 = nt * 128 + wn * 64;
#pragma unroll
  for (int ni = 0; ni < 4; ++ni) {
    int n = n0 + ni * 16 + (lane & 15);
    float bb = be[n];
#pragma unroll
    for (int mi = 0; mi < 4; ++mi) {
      int mbase = m0 + mi * 16 + (lane >> 4) * 4;
#pragma unroll
      for (int q = 0; q < 4; ++q)
        apre[(size_t)(mbase + q) * NLAT + n] = acc[mi][ni][q] + bb;
    }
  }
}

// ---------------- f32 fallback GEMM ----------------
__global__ __launch_bounds__(256) void k_encgemm_f32(
    const float* __restrict__ x, const float* __restrict__ bvec,
    const float* __restrict__ We, const float* __restrict__ be,
    float* __restrict__ apre) {
  __shared__ float As[BK][LDT];
  __shared__ float Bs[BK][LDT];
  const int t = threadIdx.x;
  const int m0 = blockIdx.x * BM;
  const int n0 = blockIdx.y * BN;
  const int lane = t & 63, wave = t >> 6;
  const int cn = ((wave & 1) * 8 + (lane & 7)) * 8;
  const int cm = ((wave >> 1) * 8 + (lane >> 3)) * 8;
  float acc[8][8] = {};
  const float* xb = x + (size_t)m0 * NIN;
  const float* wb = We + (size_t)n0 * NIN;
  for (int k0 = 0; k0 < NIN; k0 += BK) {
#pragma unroll
    for (int i = 0; i < 2; ++i) {
      int e = t + i * 256;
      int row = e >> 2, q = e & 3;
      float4 bv = *(const float4*)(bvec + k0 + q * 4);
      float4 av = *(const float4*)(xb + (size_t)row * NIN + k0 + q * 4);
      av.x -= bv.x; av.y -= bv.y; av.z -= bv.z; av.w -= bv.w;
      As[q * 4 + 0][row] = av.x; As[q * 4 + 1][row] = av.y;
      As[q * 4 + 2][row] = av.z; As[q * 4 + 3][row] = av.w;
      float4 wv = *(const float4*)(wb + (size_t)row * NIN + k0 + q * 4);
      Bs[q * 4 + 0][row] = wv.x; Bs[q * 4 + 1][row] = wv.y;
      Bs[q * 4 + 2][row] = wv.z; Bs[q * 4 + 3][row] = wv.w;
    }
    __syncthreads();
#pragma unroll
    for (int kk = 0; kk < BK; ++kk) {
      float a0[8], b0[8];
      *(float4*)&a0[0] = *(const float4*)&As[kk][cm];
      *(float4*)&a0[4] = *(const float4*)&As[kk][cm + 4];
      *(float4*)&b0[0] = *(const float4*)&Bs[kk][cn];
      *(float4*)&b0[4] = *(const float4*)&Bs[kk][cn + 4];
#pragma unroll
      for (int i = 0; i < 8; ++i)
#pragma unroll
        for (int j = 0; j < 8; ++j)
          acc[i][j] = fmaf(a0[i], b0[j], acc[i][j]);
    }
    __syncthreads();
  }
  float bb[8];
  *(float4*)&bb[0] = *(const float4*)(be + n0 + cn);
  *(float4*)&bb[4] = *(const float4*)(be + n0 + cn + 4);
#pragma unroll
  for (int i = 0; i < 8; ++i) {
    float4 v0 = make_float4(acc[i][0] + bb[0], acc[i][1] + bb[1],
                            acc[i][2] + bb[2], acc[i][3] + bb[3]);
    float4 v1 = make_float4(acc[i][4] + bb[4], acc[i][5] + bb[5],
                            acc[i][6] + bb[6], acc[i][7] + bb[7]);
    float* orow = apre + (size_t)(m0 + cm + i) * NLAT + n0 + cn;
    *(float4*)orow = v0;
    *(float4*)(orow + 4) = v1;
  }
}

// ------------- per-row analytic-threshold select + histogram rank ----
// LDS ~29KB -> 2 blocks/CU under the 64KB co-residency budget.
__global__ __launch_bounds__(1024) void k_select16(
    const float* __restrict__ apre, const float* __restrict__ x,
    const float* __restrict__ bvec, const float* __restrict__ We,
    const float* __restrict__ be, const unsigned* __restrict__ dbits,
    const int* __restrict__ kptr, const int* __restrict__ akptr,
    const int* __restrict__ ndeadP,
    int* __restrict__ cnts, int* __restrict__ mIdxG, float* __restrict__ mValG,
    int* __restrict__ aIdxG, float* __restrict__ aValG,
    int* __restrict__ bandP, int* __restrict__ flags) {
  __shared__ float redF[32];
  __shared__ float statF[4];
  __shared__ int ctrl[24];
  __shared__ int histM[256];
  __shared__ int histA[256];
  __shared__ uint2 cM[CM_CAP];
  __shared__ uint2 cA[CA_CAP];
  __shared__ uint2 bbM[BB_CAP];
  __shared__ uint2 bbA[BB_CAP];
  __shared__ int biM[BAND_CAP];
  __shared__ int biA[BAND_CAP];
  __shared__ double bvM[BAND_CAP];
  __shared__ double bvA[BAND_CAP];
  __shared__ unsigned char bsM[BAND_CAP];
  __shared__ unsigned char bsA[BAND_CAP];
  unsigned* uctrl = (unsigned*)ctrl;

  const int t = threadIdx.x;
  const int r = blockIdx.x;
  const int lane = t & 63, wave = t >> 6;   // 16 waves

  if (t < 24) ctrl[t] = 0;
  if (t >= 256 && t < 512) histM[t - 256] = 0;
  else if (t >= 512 && t < 768) histA[t - 512] = 0;

  // ---- scan 1: stats + dead bits ----
  const uint4* rowp = (const uint4*)(apre + (size_t)r * NLAT);
  unsigned dm = 0;
  float s1 = 0.f, s2 = 0.f;
#pragma unroll
  for (int i = 0; i < GRP; ++i) {
    int g = t + SELT * i;
    uint4 rv = rowp[g];
    unsigned nb = (dbits[g >> 3] >> ((g & 7) * 4)) & 0xFu;
    dm |= nb << (4 * i);
    float vs[4] = {__uint_as_float(rv.x), __uint_as_float(rv.y),
                   __uint_as_float(rv.z), __uint_as_float(rv.w)};
#pragma unroll
    for (int q = 0; q < 4; ++q) { float v = vs[q]; s1 += v; s2 += v * v; }
  }
#pragma unroll
  for (int o = 32; o; o >>= 1) { s1 += __shfl_xor(s1, o); s2 += __shfl_xor(s2, o); }
  if (lane == 0) { redF[wave] = s1; redF[16 + wave] = s2; }
  __syncthreads();
  if (wave == 0) {
    float a0 = (lane < 16) ? redF[lane] : 0.f;
    float a1 = (lane < 16) ? redF[16 + lane] : 0.f;
#pragma unroll
    for (int o = 32; o; o >>= 1) { a0 += __shfl_xor(a0, o); a1 += __shfl_xor(a1, o); }
    if (lane == 0) {
      float mu = a0 / (float)NLAT;
      float var = fmaxf(a1 / (float)NLAT - mu * mu, 1e-20f);
      statF[0] = mu; statF[1] = sqrtf(var);
    }
  }
  __syncthreads();

  int kmain = kptr[0]; if (kmain > MAIN_CAP) kmain = MAIN_CAP;
  int kaux  = akptr[0]; if (kaux > AUX_CAP)  kaux  = AUX_CAP;
  const int ndead = ndeadP[0];
  int kauxE = kaux > ndead ? ndead : kaux;
  const bool mainOn = (kmain > 0);
  const bool auxOn  = (kauxE > 0);
  const float mu = statF[0], sg = statF[1];
  unsigned TkM = 0xFFFFFFFFu, TkA = 0xFFFFFFFFu;
  if (mainOn) TkM = fkey(mu + sg * zup(8.f * kmain / (float)NLAT));
  if (auxOn) {
    float facA = (3.f * kauxE > 1280.f) ? 2.f : 3.f;
    TkA = fkey(mu + sg * zup(facA * kauxE / (float)ndead));
  }

  // ---- scan 2: extract candidates into LDS; track max key ----
  unsigned mxM = 0u, mxA = 0u;
#pragma unroll
  for (int i = 0; i < GRP; ++i) {
    int g = t + SELT * i;
    uint4 rv = rowp[g];
    unsigned nb = (dm >> (4 * i)) & 0xFu;
    float vs[4] = {__uint_as_float(rv.x), __uint_as_float(rv.y),
                   __uint_as_float(rv.z), __uint_as_float(rv.w)};
#pragma unroll
    for (int q = 0; q < 4; ++q) {
      unsigned kk = fkey(vs[q]);
      unsigned j = (unsigned)(4 * g + q);
      if (mainOn && kk >= TkM) {
        mxM = kk > mxM ? kk : mxM;
        int p = atomicAdd(&ctrl[0], 1);
        if (p < CM_CAP) { cM[p].x = kk; cM[p].y = j; }
      }
      if (auxOn && ((nb >> q) & 1u) && kk >= TkA) {
        mxA = kk > mxA ? kk : mxA;
        int p = atomicAdd(&ctrl[1], 1);
        if (p < CA_CAP) { cA[p].x = kk; cA[p].y = j; }
      }
    }
  }
#pragma unroll
  for (int o = 32; o; o >>= 1) {
    unsigned a = __shfl_xor(mxM, o); mxM = a > mxM ? a : mxM;
    unsigned b = __shfl_xor(mxA, o); mxA = b > mxA ? b : mxA;
  }
  if (lane == 0) { atomicMax(&uctrl[10], mxM); atomicMax(&uctrl[11], mxA); }
  __syncthreads();
  int ccM = ctrl[0], ccA = ctrl[1];
  bool ok = (!mainOn || (ccM >= kmain && ccM <= CM_CAP)) &&
            (!auxOn  || (ccA >= kauxE && ccA <= CA_CAP));
  if (!ok) { if (t == 0) flags[r] = 1; return; }
  if (!auxOn) ccA = 0;
  if (!mainOn) ccM = 0;
  unsigned MxM = uctrl[10], MxA = uctrl[11];
  float sclM = 255.0f / fmaxf((float)(MxM - TkM) + 1.0f, 1.0f);
  float sclA = 255.0f / fmaxf((float)(MxA - TkA) + 1.0f, 1.0f);

  // ---- histogram rank (linear) ----
  for (int c = t; c < ccM; c += 1024) {
    int b = (int)((float)(cM[c].x - TkM) * sclM);
    b = b < 0 ? 0 : (b > 255 ? 255 : b);
    atomicAdd(&histM[b], 1);
  }
  for (int c = t; c < ccA; c += 1024) {
    int b = (int)((float)(cA[c].x - TkA) * sclA);
    b = b < 0 ? 0 : (b > 255 ? 255 : b);
    atomicAdd(&histA[b], 1);
  }
  __syncthreads();
  if (t == 0 && mainOn) {
    int above = 0, b = 0;
    for (int i = 255; i >= 0; --i) {
      if (above + histM[i] >= kmain) { b = i; break; }
      above += histM[i];
    }
    ctrl[12] = b; ctrl[13] = above;
  }
  if (t == 64 && auxOn) {
    int above = 0, b = 0;
    for (int i = 255; i >= 0; --i) {
      if (above + histA[i] >= kauxE) { b = i; break; }
      above += histA[i];
    }
    ctrl[14] = b; ctrl[15] = above;
  }
  __syncthreads();
  int bM = ctrl[12], aboveM = ctrl[13];
  int bA = ctrl[14], aboveA = ctrl[15];
  for (int c = t; c < ccM; c += 1024) {
    int b = (int)((float)(cM[c].x - TkM) * sclM);
    b = b < 0 ? 0 : (b > 255 ? 255 : b);
    if (b == bM) {
      int p = atomicAdd(&ctrl[16], 1);
      if (p < BB_CAP) bbM[p] = cM[c];
    }
  }
  for (int c = t; c < ccA; c += 1024) {
    int b = (int)((float)(cA[c].x - TkA) * sclA);
    b = b < 0 ? 0 : (b > 255 ? 255 : b);
    if (b == bA) {
      int p = atomicAdd(&ctrl[17], 1);
      if (p < BB_CAP) bbA[p] = cA[c];
    }
  }
  __syncthreads();
  int nbM = ctrl[16], nbA = ctrl[17];
  if ((mainOn && nbM > BB_CAP) || (auxOn && nbA > BB_CAP)) {
    if (t == 0) flags[r] = 1;
    return;
  }
  if (!mainOn) nbM = 0;
  if (!auxOn) nbA = 0;
  if (t < nbM) {
    uint2 e = bbM[t];
    int rank = 0;
    for (int qq = 0; qq < nbM; ++qq) {
      uint2 f = bbM[qq];
      rank += (f.x > e.x || (f.x == e.x && (int)f.y < (int)e.y)) ? 1 : 0;
    }
    if (rank == kmain - aboveM - 1) ctrl[2] = (int)e.x;
  }
  if (t >= 512 && t - 512 < nbA) {
    uint2 e = bbA[t - 512];
    int rank = 0;
    for (int qq = 0; qq < nbA; ++qq) {
      uint2 f = bbA[qq];
      rank += (f.x > e.x || (f.x == e.x && (int)f.y < (int)e.y)) ? 1 : 0;
    }
    if (rank == kauxE - aboveA - 1) ctrl[3] = (int)e.x;
  }
  __syncthreads();

  // ---- bands around kth value (eps covers 1-term bf16 GEMM error) ----
  float VsM = keyinv((unsigned)ctrl[2]);
  float epsM = 1.5e-2f + 2e-3f * fabsf(VsM);
  unsigned KhiBM = mainOn ? fkey(VsM + epsM) : 0xFFFFFFFFu;
  unsigned KloBM = mainOn ? fkey(VsM - epsM) : 0xFFFFFFFFu;
  float VsA = keyinv((unsigned)ctrl[3]);
  float epsA = 1.5e-2f + 2e-3f * fabsf(VsA);
  unsigned KhiBA = auxOn ? fkey(VsA + epsA) : 0xFFFFFFFFu;
  unsigned KloBA = auxOn ? fkey(VsA - epsA) : 0xFFFFFFFFu;
  for (int c = t; c < ccM; c += 1024) {
    unsigned kk = cM[c].x;
    if (kk > KhiBM) atomicAdd(&ctrl[4], 1);
    else if (kk >= KloBM) {
      int p = atomicAdd(&ctrl[5], 1);
      if (p < BAND_CAP) biM[p] = (int)cM[c].y;
    }
  }
  for (int c = t; c < ccA; c += 1024) {
    unsigned kk = cA[c].x;
    if (kk > KhiBA) atomicAdd(&ctrl[6], 1);
    else if (kk >= KloBA) {
      int p = atomicAdd(&ctrl[7], 1);
      if (p < BAND_CAP) biA[p] = (int)cA[c].y;
    }
  }
  __syncthreads();
  if ((mainOn && ctrl[5] > BAND_CAP) || (auxOn && ctrl[7] > BAND_CAP)) {
    if (t == 0) flags[r] = 1;
    return;
  }
  if (t == 0) flags[r] = 0;
  int nAbM = ctrl[4], bcM = ctrl[5];
  int nAbA = ctrl[6], bcA = ctrl[7];
  if (!mainOn) bcM = 0;
  if (!auxOn) bcA = 0;
  int needBM = kmain - nAbM; if (needBM < 0) needBM = 0; if (needBM > bcM) needBM = bcM;
  int needBA = kauxE - nAbA; if (needBA < 0) needBA = 0; if (needBA > bcA) needBA = bcA;

  // ---- f64 band dots (wave-per-member) ----
  {
    const float* xr = x + (size_t)r * NIN;
    float xb[NIN / 64];
#pragma unroll
    for (int jj = 0; jj < NIN / 64; ++jj) {
      int col = lane + 64 * jj;
      xb[jj] = xr[col] - bvec[col];
    }
    int tot = bcM + bcA;
    for (int m = wave; m < tot; m += 16) {
      int j = (m < bcM) ? biM[m] : biA[m - bcM];
      const float* wr = We + (size_t)j * NIN;
      double s = 0.0;
#pragma unroll
      for (int jj = 0; jj < NIN / 64; ++jj)
        s += (double)xb[jj] * (double)wr[lane + 64 * jj];
#pragma unroll
      for (int o = 32; o; o >>= 1) s += __shfl_xor(s, o);
      if (lane == 0) {
        if (m < bcM) bvM[m] = s + (double)be[j];
        else bvA[m - bcM] = s + (double)be[j];
      }
    }
  }
  __syncthreads();
  if (t < bcM) {
    double vi = bvM[t]; int ii = biM[t];
    double tie = fabs(vi) * 4e-8 + 1e-12;
    int rank = 0;
    for (int qq = 0; qq < bcM; ++qq) {
      double d = bvM[qq] - vi;
      rank += ((fabs(d) <= tie) ? (biM[qq] < ii) : (d > 0.0)) ? 1 : 0;
    }
    bsM[t] = (rank < needBM) ? 1 : 0;
  }
  if (t >= 512 && t - 512 < bcA) {
    int tt = t - 512;
    double vi = bvA[tt]; int ii = biA[tt];
    double tie = fabs(vi) * 4e-8 + 1e-12;
    int rank = 0;
    for (int qq = 0; qq < bcA; ++qq) {
      double d = bvA[qq] - vi;
      rank += ((fabs(d) <= tie) ? (biA[qq] < ii) : (d > 0.0)) ? 1 : 0;
    }
    bsA[tt] = (rank < needBA) ? 1 : 0;
  }
  __syncthreads();

  // ---- selected lists from candidates ----
  for (int c = t; c < ccM; c += 1024) {
    unsigned kk = cM[c].x; int j = (int)cM[c].y;
    bool sel = kk > KhiBM;
    if (!sel && kk >= KloBM) {
      for (int m2 = 0; m2 < bcM; ++m2)
        if (biM[m2] == j) { sel = bsM[m2] != 0; break; }
    }
    float v = keyinv(kk);
    if (sel && v != 0.0f) {
      int p = atomicAdd(&ctrl[8], 1);
      if (p < MAIN_CAP) { mIdxG[r * MAIN_CAP + p] = j; mValG[r * MAIN_CAP + p] = v; }
    }
  }
  for (int c = t; c < ccA; c += 1024) {
    unsigned kk = cA[c].x; int j = (int)cA[c].y;
    bool sel = kk > KhiBA;
    if (!sel && kk >= KloBA) {
      for (int m2 = 0; m2 < bcA; ++m2)
        if (biA[m2] == j) { sel = bsA[m2] != 0; break; }
    }
    float v = keyinv(kk);
    if (sel && v != 0.0f) {
      int p = atomicAdd(&ctrl[9], 1);
      if (p < AUX_CAP) { aIdxG[r * AUX_CAP + p] = j; aValG[r * AUX_CAP + p] = v; }
    }
  }
  __syncthreads();
  int* bp = bandP + (size_t)r * BPSTRIDE;
  if (t == 0) {
    cnts[2 * r] = ctrl[8] < MAIN_CAP ? ctrl[8] : MAIN_CAP;
    cnts[2 * r + 1] = auxOn ? (ctrl[9] < AUX_CAP ? ctrl[9] : AUX_CAP) : 0;
    bp[0] = (int)KhiBM; bp[1] = (int)KloBM; bp[2] = bcM;
  }
  if (t < bcM) bp[3 + t] = (biM[t] << 1) | (int)bsM[t];
}

// ------------- streaming dense alpha/mask emit ----
__global__ __launch_bounds__(256) void k_emit(
    const float* apre, const int* __restrict__ flags,
    const int* __restrict__ bandP, float* __restrict__ alpha, float* mask) {
  const int bid = blockIdx.x;
  const int r = bid / 3, c = bid % 3;   // 3 chunks x 8192 elems
  if (flags[r]) return;
  __shared__ int hdr[3];
  __shared__ int bent[BAND_CAP];
  const int t = threadIdx.x;
  const int* bp = bandP + (size_t)r * BPSTRIDE;
  if (t < 3) hdr[t] = bp[t];
  __syncthreads();
  int bc = hdr[2];
  if (t < bc) bent[t] = bp[3 + t];
  __syncthreads();
  unsigned KhiB = (unsigned)hdr[0], KloB = (unsigned)hdr[1];
  const float4* src = (const float4*)(apre + (size_t)r * NLAT) + c * 2048;
  float4* adst = (float4*)(alpha + (size_t)r * NLAT) + c * 2048;
  float4* mdst = (float4*)(mask + (size_t)r * NLAT) + c * 2048;
  const int ebase = c * 8192;
#pragma unroll
  for (int i = 0; i < 8; ++i) {
    int g = t + 256 * i;
    float4 v4 = src[g];
    float vs[4] = {v4.x, v4.y, v4.z, v4.w};
    float av[4], mv[4];
#pragma unroll
    for (int q = 0; q < 4; ++q) {
      float v = vs[q];
      unsigned kk = fkey(v);
      int j = ebase + 4 * g + q;
      bool sel = kk > KhiB;
      if (!sel && kk >= KloB) {
        for (int m = 0; m < bc; ++m)
          if ((bent[m] >> 1) == j) { sel = (bent[m] & 1) != 0; break; }
      }
      av[q] = sel ? v : 0.0f;
      mv[q] = (sel && v != 0.0f) ? 1.0f : 0.0f;
    }
    adst[g] = make_float4(av[0], av[1], av[2], av[3]);
    mdst[g] = make_float4(mv[0], mv[1], mv[2], mv[3]);
  }
}

// ------------- fallback: 16-bit-key full select, gated on flags ----
__global__ __launch_bounds__(SELT) void k_selectFB(
    const float* apre, const float* __restrict__ x,
    const float* __restrict__ bvec, const float* __restrict__ We,
    const float* __restrict__ be, const unsigned* __restrict__ dbits,
    const int* __restrict__ kptr, const int* __restrict__ akptr,
    float* __restrict__ alpha, float* mask,
    int* __restrict__ cnts, int* __restrict__ mIdxG, float* __restrict__ mValG,
    int* __restrict__ aIdxG, float* __restrict__ aValG,
    const int* __restrict__ flags) {
  if (flags[blockIdx.x] == 0) return;
  extern __shared__ char smem[];
  uint2*    keys2 = (uint2*)(smem + OFF_K16);
  float*    redF  = (float*)(smem + OFF_REDF);
  int*      redI  = (int*)(smem + OFF_REDI);
  int*      ctrl  = (int*)(smem + OFF_CTRL);
  float*    ctrlF = (float*)(smem + OFF_CTRL);
  int*      pcnt  = (int*)(smem + OFF_PCNT);
  unsigned* ckM   = (unsigned*)(smem + OFF_CKM);
  int*      ciM   = (int*)(smem + OFF_CIM);
  unsigned* ckA   = (unsigned*)(smem + OFF_CKA);
  int*      ciA   = (int*)(smem + OFF_CIA);
  int*      biM   = (int*)(smem + OFF_BIM);
  int*      biA   = (int*)(smem + OFF_BIA);
  double*   bvM   = (double*)(smem + OFF_BVM);
  double*   bvA   = (double*)(smem + OFF_BVA);
  unsigned char* bsM = (unsigned char*)(smem + OFF_BSM);
  unsigned char* bsA = (unsigned char*)(smem + OFF_BSA);

  const int t = threadIdx.x;
  const int r = blockIdx.x;
  const int lane = t & 63, wave = t >> 6;

  if (t < 96) pcnt[t] = 0;
  else if (t < 108) ctrl[t - 96] = 0;

  const uint4* rowp = (const uint4*)(apre + (size_t)r * NLAT);
  const float* rowf = apre + (size_t)r * NLAT;
  unsigned dm = 0;
  float s1 = 0.f, s2 = 0.f;
  float vmxA = -INFINITY, vmnA = INFINITY, vmxD = -INFINITY, vmnD = INFINITY;
#pragma unroll
  for (int i = 0; i < GRP; ++i) {
    int g = t + SELT * i;
    uint4 rv = rowp[g];
    unsigned nb = (dbits[g >> 3] >> ((g & 7) * 4)) & 0xFu;
    dm |= nb << (4 * i);
    float vs[4] = {__uint_as_float(rv.x), __uint_as_float(rv.y),
                   __uint_as_float(rv.z), __uint_as_float(rv.w)};
    unsigned k16[4];
#pragma unroll
    for (int q = 0; q < 4; ++q) {
      float v = vs[q];
      k16[q] = fkey(v) >> 16;
      s1 += v; s2 += v * v;
      vmxA = fmaxf(vmxA, v); vmnA = fminf(vmnA, v);
      if ((nb >> q) & 1u) { vmxD = fmaxf(vmxD, v); vmnD = fminf(vmnD, v); }
    }
    uint2 kp2;
    kp2.x = k16[0] | (k16[1] << 16);
    kp2.y = k16[2] | (k16[3] << 16);
    keys2[g] = kp2;
  }
  int nd = __popc(dm & 0xFFFFFFu);
#pragma unroll
  for (int o = 32; o; o >>= 1) {
    s1 += __shfl_xor(s1, o); s2 += __shfl_xor(s2, o);
    vmxA = fmaxf(vmxA, __shfl_xor(vmxA, o)); vmnA = fminf(vmnA, __shfl_xor(vmnA, o));
    vmxD = fmaxf(vmxD, __shfl_xor(vmxD, o)); vmnD = fminf(vmnD, __shfl_xor(vmnD, o));
    nd += __shfl_xor(nd, o);
  }
  if (lane == 0) {
    float* rf = redF + wave * 8;
    rf[0] = s1; rf[1] = s2; rf[2] = vmxA; rf[3] = vmnA; rf[4] = vmxD; rf[5] = vmnD;
    redI[wave] = nd;
  }
  __syncthreads();
  if (wave == 0) {
    float a0 = 0.f, a1 = 0.f, a2 = -INFINITY, a3 = INFINITY, a4 = -INFINITY, a5 = INFINITY;
    int a6 = 0;
    if (lane < 16) {
      const float* rf = redF + lane * 8;
      a0 = rf[0]; a1 = rf[1]; a2 = rf[2]; a3 = rf[3]; a4 = rf[4]; a5 = rf[5];
      a6 = redI[lane];
    }
#pragma unroll
    for (int o = 32; o; o >>= 1) {
      a0 += __shfl_xor(a0, o); a1 += __shfl_xor(a1, o);
      a2 = fmaxf(a2, __shfl_xor(a2, o)); a3 = fminf(a3, __shfl_xor(a3, o));
      a4 = fmaxf(a4, __shfl_xor(a4, o)); a5 = fminf(a5, __shfl_xor(a5, o));
      a6 += __shfl_xor(a6, o);
    }
    if (lane == 0) {
      float mu = a0 / (float)NLAT;
      float var = fmaxf(a1 / (float)NLAT - mu * mu, 1e-20f);
      ctrlF[16] = mu; ctrlF[17] = sqrtf(var);
      ctrlF[18] = a3; ctrlF[19] = a2;
      ctrlF[20] = a5; ctrlF[21] = a4;
      ctrl[22] = a6;
    }
  }
  __syncthreads();

  int kmain = kptr[0]; if (kmain > MAIN_CAP) kmain = MAIN_CAP;
  int kaux  = akptr[0]; if (kaux > AUX_CAP)  kaux  = AUX_CAP;
  const float mu = ctrlF[16], sg = ctrlF[17];
  const int ndead = ctrl[22];
  int kauxE = kaux > ndead ? ndead : kaux;
  const bool mainOn = (kmain > 0);
  const bool auxOn  = (kauxE > 0);

  unsigned TloM = fkey(ctrlF[18]) >> 16, ThiM = (fkey(ctrlF[19]) >> 16) + 1u;
  int cLoM = NLAT, cHiM = 0;
  unsigned TloA = 0u, ThiA = 2u;
  int cLoA = 0, cHiA = 0;
  if (auxOn) { TloA = fkey(ctrlF[20]) >> 16; ThiA = (fkey(ctrlF[21]) >> 16) + 1u; cLoA = ndead; }

  for (int it = 0; it < 16; ++it) {
    bool actM = mainOn && (cLoM - cHiM) > (CAND_CAP - 8) && (ThiM - TloM) > 1u;
    bool actA = auxOn  && (cLoA - cHiA) > (CAND_CAP - 8) && (ThiA - TloA) > 1u;
    if (!actM && !actA) break;
    unsigned TM1 = TloM + 1u, TM2 = TM1, TM3 = TM1;
    unsigned TA1 = TloA + 1u, TA2 = TA1, TA3 = TA1;
    if (actM) {
      unsigned lo1 = TloM + 1u, hi1 = ThiM - 1u;
      if (it == 0) {
        float fn = (float)NLAT;
        TM1 = fkey(mu + sg * zup(4.f * kmain / fn)) >> 16;
        TM2 = fkey(mu + sg * zup((float)kmain / fn)) >> 16;
        TM3 = fkey(mu + sg * zup(0.25f * kmain / fn)) >> 16;
      } else {
        float vlo = keyinv(TloM << 16), vhi = keyinv((ThiM << 16) - 1u);
        TM1 = fkey(0.75f * vlo + 0.25f * vhi) >> 16;
        TM2 = fkey(0.50f * vlo + 0.50f * vhi) >> 16;
        TM3 = fkey(0.25f * vlo + 0.75f * vhi) >> 16;
      }
      TM1 = TM1 < lo1 ? lo1 : (TM1 > hi1 ? hi1 : TM1);
      TM2 = TM2 < TM1 ? TM1 : (TM2 > hi1 ? hi1 : TM2);
      TM3 = TM3 < TM2 ? TM2 : (TM3 > hi1 ? hi1 : TM3);
    }
    if (actA) {
      unsigned lo1 = TloA + 1u, hi1 = ThiA - 1u;
      if (it == 0) {
        float fn = (float)ndead;
        TA1 = fkey(mu + sg * zup(4.f * kauxE / fn)) >> 16;
        TA2 = fkey(mu + sg * zup((float)kauxE / fn)) >> 16;
        TA3 = fkey(mu + sg * zup(0.25f * kauxE / fn)) >> 16;
      } else {
        float vlo = keyinv(TloA << 16), vhi = keyinv((ThiA << 16) - 1u);
        TA1 = fkey(0.75f * vlo + 0.25f * vhi) >> 16;
        TA2 = fkey(0.50f * vlo + 0.50f * vhi) >> 16;
        TA3 = fkey(0.25f * vlo + 0.75f * vhi) >> 16;
      }
      TA1 = TA1 < lo1 ? lo1 : (TA1 > hi1 ? hi1 : TA1);
      TA2 = TA2 < TA1 ? TA1 : (TA2 > hi1 ? hi1 : TA2);
      TA3 = TA3 < TA2 ? TA2 : (TA3 > hi1 ? hi1 : TA3);
    }
    int cm1 = 0, cm2 = 0, cm3 = 0, ca1 = 0, ca2 = 0, ca3 = 0;
#pragma unroll
    for (int i = 0; i < GRP; ++i) {
      uint2 kv = keys2[t + SELT * i];
      unsigned nb = (dm >> (4 * i)) & 0xFu;
      unsigned ks[4] = {kv.x & 0xFFFFu, kv.x >> 16, kv.y & 0xFFFFu, kv.y >> 16};
#pragma unroll
      for (int q = 0; q < 4; ++q) {
        unsigned kk = ks[q];
        cm1 += (kk >= TM1); cm2 += (kk >= TM2); cm3 += (kk >= TM3);
        if ((nb >> q) & 1u) { ca1 += (kk >= TA1); ca2 += (kk >= TA2); ca3 += (kk >= TA3); }
      }
    }
#pragma unroll
    for (int o = 32; o; o >>= 1) {
      cm1 += __shfl_xor(cm1, o); cm2 += __shfl_xor(cm2, o); cm3 += __shfl_xor(cm3, o);
      ca1 += __shfl_xor(ca1, o); ca2 += __shfl_xor(ca2, o); ca3 += __shfl_xor(ca3, o);
    }
    if (lane == 0) {
      int* pc = pcnt + it * 6;
      atomicAdd(&pc[0], cm1); atomicAdd(&pc[1], cm2); atomicAdd(&pc[2], cm3);
      atomicAdd(&pc[3], ca1); atomicAdd(&pc[4], ca2); atomicAdd(&pc[5], ca3);
    }
    __syncthreads();
    const int* pc = pcnt + it * 6;
    int CM1 = pc[0], CM2 = pc[1], CM3 = pc[2];
    int CA1 = pc[3], CA2 = pc[4], CA3 = pc[5];
    if (actM) {
      if (CM3 >= kmain)      { TloM = TM3; cLoM = CM3; }
      else if (CM2 >= kmain) { TloM = TM2; cLoM = CM2; ThiM = TM3; cHiM = CM3; }
      else if (CM1 >= kmain) { TloM = TM1; cLoM = CM1; ThiM = TM2; cHiM = CM2; }
      else                   { ThiM = TM1; cHiM = CM1; }
    }
    if (actA) {
      if (CA3 >= kauxE)      { TloA = TA3; cLoA = CA3; }
      else if (CA2 >= kauxE) { TloA = TA2; cLoA = CA2; ThiA = TA3; cHiA = CA3; }
      else if (CA1 >= kauxE) { TloA = TA1; cLoA = CA1; ThiA = TA2; cHiA = CA2; }
      else                   { ThiA = TA1; cHiA = CA1; }
    }
  }

#pragma unroll
  for (int i = 0; i < GRP; ++i) {
    int g = t + SELT * i;
    uint2 kv = keys2[g];
    unsigned nb = (dm >> (4 * i)) & 0xFu;
    unsigned ks[4] = {kv.x & 0xFFFFu, kv.x >> 16, kv.y & 0xFFFFu, kv.y >> 16};
#pragma unroll
    for (int q = 0; q < 4; ++q) {
      unsigned kk = ks[q];
      int j = 4 * g + q;
      if (mainOn && kk >= TloM && kk < ThiM) {
        int p = atomicAdd(&ctrl[0], 1);
        if (p < CAND_CAP) { ckM[p] = fkey(rowf[j]); ciM[p] = j; }
      }
      if (auxOn && ((nb >> q) & 1u) && kk >= TloA && kk < ThiA) {
        int p = atomicAdd(&ctrl[1], 1);
        if (p < CAND_CAP) { ckA[p] = fkey(rowf[j]); ciA[p] = j; }
      }
    }
  }
  __syncthreads();
  int ccM = ctrl[0] < CAND_CAP ? ctrl[0] : CAND_CAP;
  int ccA = ctrl[1] < CAND_CAP ? ctrl[1] : CAND_CAP;
  int needM = kmain - cHiM; if (needM < 1) needM = 1; if (needM > ccM) needM = ccM;
  int needA = kauxE - cHiA; if (needA < 1) needA = 1; if (needA > ccA) needA = ccA;

  if (t < ccM) {
    unsigned ki = ckM[t]; int ii = ciM[t];
    int rank = 0;
    for (int qq = 0; qq < ccM; ++qq) {
      unsigned kq = ckM[qq];
      rank += (kq > ki || (kq == ki && ciM[qq] < ii)) ? 1 : 0;
    }
    if (rank == needM - 1) ctrl[2] = (int)ki;
  } else if (t >= 512 && t - 512 < ccA) {
    int tt = t - 512;
    unsigned ki = ckA[tt]; int ii = ciA[tt];
    int rank = 0;
    for (int qq = 0; qq < ccA; ++qq) {
      unsigned kq = ckA[qq];
      rank += (kq > ki || (kq == ki && ciA[qq] < ii)) ? 1 : 0;
    }
    if (rank == needA - 1) ctrl[3] = (int)ki;
  }
  __syncthreads();

  float VsM = keyinv((unsigned)ctrl[2]);
  float epsM = 1.5e-2f + 2e-3f * fabsf(VsM);
  unsigned KhiBM = mainOn ? fkey(VsM + epsM) : 0xFFFFFFFFu;
  unsigned KloBM = mainOn ? fkey(VsM - epsM) : 0xFFFFFFFFu;
  float VsA = keyinv((unsigned)ctrl[3]);
  float epsA = 1.5e-2f + 2e-3f * fabsf(VsA);
  unsigned KhiBA = auxOn ? fkey(VsA + epsA) : 0xFFFFFFFFu;
  unsigned KloBA = auxOn ? fkey(VsA - epsA) : 0xFFFFFFFFu;
  unsigned KhiBM16 = KhiBM >> 16, KloBM16 = KloBM >> 16;
  unsigned KhiBA16 = KhiBA >> 16, KloBA16 = KloBA >> 16;
  int abvM = 0, abvA = 0;
#pragma unroll
  for (int i = 0; i < GRP; ++i) {
    int g = t + SELT * i;
    uint2 kv = keys2[g];
    unsigned nb = (dm >> (4 * i)) & 0xFu;
    unsigned ks[4] = {kv.x & 0xFFFFu, kv.x >> 16, kv.y & 0xFFFFu, kv.y >> 16};
#pragma unroll
    for (int q = 0; q < 4; ++q) {
      unsigned kk = ks[q];
      int j = 4 * g + q;
      if (mainOn) {
        if (kk > KhiBM16) ++abvM;
        else if (kk >= KloBM16) {
          unsigned kf = fkey(rowf[j]);
          if (kf > KhiBM) ++abvM;
          else if (kf >= KloBM) {
            int p = atomicAdd(&ctrl[5], 1);
            if (p < BAND_CAP) biM[p] = j;
          }
        }
      }
      if (auxOn && ((nb >> q) & 1u)) {
        if (kk > KhiBA16) ++abvA;
        else if (kk >= KloBA16) {
          unsigned kf = fkey(rowf[j]);
          if (kf > KhiBA) ++abvA;
          else if (kf >= KloBA) {
            int p = atomicAdd(&ctrl[7], 1);
            if (p < BAND_CAP) biA[p] = j;
          }
        }
      }
    }
  }
#pragma unroll
  for (int o = 32; o; o >>= 1) { abvM += __shfl_xor(abvM, o); abvA += __shfl_xor(abvA, o); }
  if (lane == 0) { atomicAdd(&ctrl[4], abvM); atomicAdd(&ctrl[6], abvA); }
  __syncthreads();
  int nAbM = ctrl[4], bcM = ctrl[5] < BAND_CAP ? ctrl[5] : BAND_CAP;
  int nAbA = ctrl[6], bcA = auxOn ? (ctrl[7] < BAND_CAP ? ctrl[7] : BAND_CAP) : 0;
  if (!mainOn) bcM = 0;
  int needBM = kmain - nAbM; if (needBM < 0) needBM = 0; if (needBM > bcM) needBM = bcM;
  int needBA = kauxE - nAbA; if (needBA < 0) needBA = 0; if (needBA > bcA) needBA = bcA;

  {
    const float* xr = x + (size_t)r * NIN;
    float xb[NIN / 64];
#pragma unroll
    for (int jj = 0; jj < NIN / 64; ++jj) {
      int col = lane + 64 * jj;
      xb[jj] = xr[col] - bvec[col];
    }
    int tot = bcM + bcA;
    for (int m = wave; m < tot; m += 16) {
      int j = (m < bcM) ? biM[m] : biA[m - bcM];
      const float* wr = We + (size_t)j * NIN;
      double s = 0.0;
#pragma unroll
      for (int jj = 0; jj < NIN / 64; ++jj)
        s += (double)xb[jj] * (double)wr[lane + 64 * jj];
#pragma unroll
      for (int o = 32; o; o >>= 1) s += __shfl_xor(s, o);
      if (lane == 0) {
        if (m < bcM) bvM[m] = s + (double)be[j];
        else bvA[m - bcM] = s + (double)be[j];
      }
    }
  }
  __syncthreads();
  if (t < bcM) {
    double vi = bvM[t]; int ii = biM[t];
    double tie = fabs(vi) * 4e-8 + 1e-12;
    int rank = 0;
    for (int qq = 0; qq < bcM; ++qq) {
      double d = bvM[qq] - vi;
      rank += ((fabs(d) <= tie) ? (biM[qq] < ii) : (d > 0.0)) ? 1 : 0;
    }
    bsM[t] = (rank < needBM) ? 1 : 0;
  } else if (t >= 512 && t - 512 < bcA) {
    int tt = t - 512;
    double vi = bvA[tt]; int ii = biA[tt];
    double tie = fabs(vi) * 4e-8 + 1e-12;
    int rank = 0;
    for (int qq = 0; qq < bcA; ++qq) {
      double d = bvA[qq] - vi;
      rank += ((fabs(d) <= tie) ? (biA[qq] < ii) : (d > 0.0)) ? 1 : 0;
    }
    bsA[tt] = (rank < needBA) ? 1 : 0;
  }
  __syncthreads();

  {
    float4* arow = (float4*)(alpha + (size_t)r * NLAT);
    float4* mrow = (float4*)(mask + (size_t)r * NLAT);
#pragma unroll
    for (int i = 0; i < GRP; ++i) {
      int g = t + SELT * i;
      uint4 rv = rowp[g];
      unsigned nb = (dm >> (4 * i)) & 0xFu;
      float vs[4] = {__uint_as_float(rv.x), __uint_as_float(rv.y),
                     __uint_as_float(rv.z), __uint_as_float(rv.w)};
      float av[4], mv[4];
#pragma unroll
      for (int q = 0; q < 4; ++q) {
        float v = vs[q];
        unsigned kk = fkey(v);
        int j = 4 * g + q;
        bool selM = mainOn && (kk > KhiBM);
        if (mainOn && !selM && kk >= KloBM) {
          for (int m2 = 0; m2 < bcM; ++m2)
            if (biM[m2] == j) { selM = bsM[m2] != 0; break; }
        }
        bool nz = selM && (v != 0.0f);
        av[q] = selM ? v : 0.0f;
        mv[q] = nz ? 1.0f : 0.0f;
        if (nz) {
          int p = atomicAdd(&ctrl[8], 1);
          if (p < MAIN_CAP) { mIdxG[r * MAIN_CAP + p] = j; mValG[r * MAIN_CAP + p] = v; }
        }
        if (auxOn && ((nb >> q) & 1u)) {
          bool selA = kk > KhiBA;
          if (!selA && kk >= KloBA) {
            for (int m2 = 0; m2 < bcA; ++m2)
              if (biA[m2] == j) { selA = bsA[m2] != 0; break; }
          }
          if (selA && v != 0.0f) {
            int p = atomicAdd(&ctrl[9], 1);
            if (p < AUX_CAP) { aIdxG[r * AUX_CAP + p] = j; aValG[r * AUX_CAP + p] = v; }
          }
        }
      }
      arow[g] = make_float4(av[0], av[1], av[2], av[3]);
      mrow[g] = make_float4(mv[0], mv[1], mv[2], mv[3]);
    }
  }
  __syncthreads();
  if (t == 0) {
    cnts[2 * r] = ctrl[8] < MAIN_CAP ? ctrl[8] : MAIN_CAP;
    cnts[2 * r + 1] = auxOn ? (ctrl[9] < AUX_CAP ? ctrl[9] : AUX_CAP) : 0;
  }
}

// ------------- decode ----
__global__ __launch_bounds__(256) void k_decode(
    const int* __restrict__ cnts, const int* __restrict__ mIdxG,
    const float* __restrict__ mValG, const int* __restrict__ aIdxG,
    const float* __restrict__ aValG, const float* __restrict__ bvec,
    const __bf16* __restrict__ Wt, const float* __restrict__ Wd,
    float* __restrict__ xhat, float* __restrict__ auxo) {
  const int r = blockIdx.x, t = threadIdx.x;
  __shared__ int sMi[MAIN_CAP];
  __shared__ float sMv[MAIN_CAP];
  __shared__ int sAi[AUX_CAP];
  __shared__ float sAv[AUX_CAP];
  int kc = cnts[2 * r], ac = cnts[2 * r + 1];
  if (t < MAIN_CAP && t < kc) { sMi[t] = mIdxG[r * MAIN_CAP + t]; sMv[t] = mValG[r * MAIN_CAP + t]; }
  for (int i = t; i < ac; i += 256) { sAi[i] = aIdxG[r * AUX_CAP + i]; sAv[i] = aValG[r * AUX_CAP + i]; }
  __syncthreads();

  float o0 = 0.f, o1 = 0.f, o2 = 0.f;
  float a0 = 0.f, a1 = 0.f, a2 = 0.f;
  if (Wt) {
    int i = 0;
    for (; i + 4 <= kc; i += 4) {
      int i0 = sMi[i], i1 = sMi[i + 1], i2 = sMi[i + 2], i3 = sMi[i + 3];
      float v0 = sMv[i], v1 = sMv[i + 1], v2 = sMv[i + 2], v3 = sMv[i + 3];
      const __bf16* p0 = Wt + (size_t)i0 * NIN;
      const __bf16* p1 = Wt + (size_t)i1 * NIN;
      const __bf16* p2 = Wt + (size_t)i2 * NIN;
      const __bf16* p3 = Wt + (size_t)i3 * NIN;
      float w00 = p0[t], w01 = p0[t + 256], w02 = p0[t + 512];
      float w10 = p1[t], w11 = p1[t + 256], w12 = p1[t + 512];
      float w20 = p2[t], w21 = p2[t + 256], w22 = p2[t + 512];
      float w30 = p3[t], w31 = p3[t + 256], w32 = p3[t + 512];
      o0 = fmaf(v0, w00, o0); o1 = fmaf(v0, w01, o1); o2 = fmaf(v0, w02, o2);
      o0 = fmaf(v1, w10, o0); o1 = fmaf(v1, w11, o1); o2 = fmaf(v1, w12, o2);
      o0 = fmaf(v2, w20, o0); o1 = fmaf(v2, w21, o1); o2 = fmaf(v2, w22, o2);
      o0 = fmaf(v3, w30, o0); o1 = fmaf(v3, w31, o1); o2 = fmaf(v3, w32, o2);
    }
    for (; i < kc; ++i) {
      const __bf16* p = Wt + (size_t)sMi[i] * NIN;
      float v = sMv[i];
      o0 = fmaf(v, (float)p[t], o0);
      o1 = fmaf(v, (float)p[t + 256], o1);
      o2 = fmaf(v, (float)p[t + 512], o2);
    }
    i = 0;
    for (; i + 4 <= ac; i += 4) {
      int i0 = sAi[i], i1 = sAi[i + 1], i2 = sAi[i + 2], i3 = sAi[i + 3];
      float v0 = sAv[i], v1 = sAv[i + 1], v2 = sAv[i + 2], v3 = sAv[i + 3];
      const __bf16* p0 = Wt + (size_t)i0 * NIN;
      const __bf16* p1 = Wt + (size_t)i1 * NIN;
      const __bf16* p2 = Wt + (size_t)i2 * NIN;
      const __bf16* p3 = Wt + (size_t)i3 * NIN;
      float w00 = p0[t], w01 = p0[t + 256], w02 = p0[t + 512];
      float w10 = p1[t], w11 = p1[t + 256], w12 = p1[t + 512];
      float w20 = p2[t], w21 = p2[t + 256], w22 = p2[t + 512];
      float w30 = p3[t], w31 = p3[t + 256], w32 = p3[t + 512];
      a0 = fmaf(v0, w00, a0); a1 = fmaf(v0, w01, a1); a2 = fmaf(v0, w02, a2);
      a0 = fmaf(v1, w10, a0); a1 = fmaf(v1, w11, a1); a2 = fmaf(v1, w12, a2);
      a0 = fmaf(v2, w20, a0); a1 = fmaf(v2, w21, a1); a2 = fmaf(v2, w22, a2);
      a0 = fmaf(v3, w30, a0); a1 = fmaf(v3, w31, a1); a2 = fmaf(v3, w32, a2);
    }
    for (; i < ac; ++i) {
      const __bf16* p = Wt + (size_t)sAi[i] * NIN;
      float v = sAv[i];
      a0 = fmaf(v, (float)p[t], a0);
      a1 = fmaf(v, (float)p[t + 256], a1);
      a2 = fmaf(v, (float)p[t + 512], a2);
    }
  } else {
    for (int i = 0; i < kc; ++i) {
      float v = sMv[i]; int ix = sMi[i];
      o0 = fmaf(v, Wd[(size_t)t * NLAT + ix], o0);
      o1 = fmaf(v, Wd[(size_t)(t + 256) * NLAT + ix], o1);
      o2 = fmaf(v, Wd[(size_t)(t + 512) * NLAT + ix], o2);
    }
    for (int i = 0; i < ac; ++i) {
      float v = sAv[i]; int ix = sAi[i];
      a0 = fmaf(v, Wd[(size_t)t * NLAT + ix], a0);
      a1 = fmaf(v, Wd[(size_t)(t + 256) * NLAT + ix], a1);
      a2 = fmaf(v, Wd[(size_t)(t + 512) * NLAT + ix], a2);
    }
  }
  float b0 = bvec[t], b1 = bvec[t + 256], b2 = bvec[t + 512];
  xhat[(size_t)r * NIN + t] = o0 + b0;
  xhat[(size_t)r * NIN + t + 256] = o1 + b1;
  xhat[(size_t)r * NIN + t + 512] = o2 + b2;
  auxo[(size_t)r * NIN + t] = a0 + b0;
  auxo[(size_t)r * NIN + t + 256] = a1 + b1;
  auxo[(size_t)r * NIN + t + 512] = a2 + b2;
}

extern "C" void kernel_launch(void* const* d_in, const int* in_sizes, int n_in,
                              void* d_out, int out_size, void* d_ws, size_t ws_size,
                              hipStream_t stream) {
  const float* x  = (const float*)d_in[0];
  const float* bv = (const float*)d_in[1];
  const float* We = (const float*)d_in[2];
  const float* be = (const float*)d_in[3];
  const float* Wd = (const float*)d_in[4];
  const int* miss = (const int*)d_in[5];
  const int* kp   = (const int*)d_in[6];
  const int* akp  = (const int*)d_in[7];

  float* out   = (float*)d_out;
  float* xhat  = out;
  float* alpha = out + (size_t)3145728;
  float* apre  = out + (size_t)103809024;
  float* auxo  = out + (size_t)204472320;

  char* wsb = (char*)d_ws;
  size_t o = 0;
  unsigned* dbits = (unsigned*)(wsb + o); o += 65536;
  int*   cnts  = (int*)(wsb + o); o += 65536;
  int*   mIdxG = (int*)(wsb + o); o += (size_t)NB * MAIN_CAP * 4;
  float* mValG = (float*)(wsb + o); o += (size_t)NB * MAIN_CAP * 4;
  int*   aIdxG = (int*)(wsb + o); o += (size_t)NB * AUX_CAP * 4;
  float* aValG = (float*)(wsb + o); o += (size_t)NB * AUX_CAP * 4;
  int*   bandP = (int*)(wsb + o); o += (size_t)NB * BPSTRIDE * 4;
  int*   flags = (int*)(wsb + o); o += 65536;
  int*   ndead = (int*)(wsb + o); o += 65536;
  size_t offWt = o;
  size_t offA2 = offWt + (size_t)NLAT * NIN * 2;
  size_t offB2 = offA2 + (size_t)NB * K2 * 2;
  size_t needFull = offB2 + (size_t)NLAT * K2 * 2;
  bool haveWt   = ws_size >= offA2;
  bool haveFull = ws_size >= needFull;
  __bf16* Wt = haveWt ? (__bf16*)(wsb + offWt) : nullptr;
  __bf16* A2 = (__bf16*)(wsb + offA2);
  __bf16* B2 = (__bf16*)(wsb + offB2);

  k_deadbits<<<96, 256, 0, stream>>>(miss, dbits);
  k_ndead<<<1, 256, 0, stream>>>(dbits, ndead);
  if (haveFull) {
    k_pack_a<<<dim3(32, KT2), 256, 0, stream>>>(x, bv, A2);
    k_pack_b<<<dim3(192, KT2), 256, 0, stream>>>(We, B2);
  }
  if (haveWt)
    k_transpose<<<dim3(NLAT / 32, NIN / 32), dim3(32, 8), 0, stream>>>(Wd, Wt);

  if (haveFull)
    k_gemm_bf16<<<dim3(32, 192), 256, 0, stream>>>(A2, B2, be, apre);
  else
    k_encgemm_f32<<<dim3(NB / BM, NLAT / BN), 256, 0, stream>>>(x, bv, We, be, apre);

  k_select16<<<NB, 1024, 0, stream>>>(apre, x, bv, We, be, dbits, kp, akp, ndead,
                                      cnts, mIdxG, mValG, aIdxG, aValG, bandP, flags);
  k_selectFB<<<NB, SELT, SMEM_SEL, stream>>>(apre, x, bv, We, be, dbits, kp, akp,
                                             alpha, apre, cnts, mIdxG, mValG,
                                             aIdxG, aValG, flags);
  k_emit<<<NB * 3, 256, 0, stream>>>(apre, flags, bandP, alpha, apre);
  k_decode<<<NB, 256, 0, stream>>>(cnts, mIdxG, mValG, aIdxG, aValG, bv,
                                   Wt, Wd, xhat, auxo);
}